// Round 20
// baseline (1588.971 us; speedup 1.0000x reference)
//
#include <hip/hip_runtime.h>
#include <hip/hip_bf16.h>
#include <stdint.h>

#define NLAYERS 8
#define LSEQ 576
#define EMB 768
#define NHEAD 12
#define HDIM 64
#define FFDIM 3072
#define BLROWS 4608   // B*L

typedef __attribute__((ext_vector_type(8))) short short8;
typedef __attribute__((ext_vector_type(4))) short short4v;
typedef __attribute__((ext_vector_type(4))) float floatx4;

__device__ __forceinline__ float b2f(short s) {
    union { float f; uint32_t u; } x; x.u = ((uint32_t)(uint16_t)s) << 16; return x.f;
}
__device__ __forceinline__ short f2b(float f) {
    union { float f; uint32_t u; } x; x.f = f;
    uint32_t r = x.u + 0x7fffu + ((x.u >> 16) & 1u);
    return (short)(r >> 16);
}

#define GLDS16(gp, lp) __builtin_amdgcn_global_load_lds( \
    (const __attribute__((address_space(1))) void*)(gp), \
    (__attribute__((address_space(3))) void*)(lp), 16, 0, 0)

// bijective XCD-chunked remap (m204)
__device__ __forceinline__ void xcd_remap(int& bx, int& by) {
    const int gx = gridDim.x;
    const int n  = gx * gridDim.y;
    const int orig = by * gx + bx;
    const int q = n >> 3, r = n & 7;
    const int xcd = orig & 7;
    const int wgid = (xcd < r ? xcd * (q + 1) : r * (q + 1) + (xcd - r) * q) + (orig >> 3);
    bx = wgid % gx;
    by = wgid / gx;
}

// ---------------- GEMM: C[M,N] = A[M,K](bf16) * Bt[N,K]^T (bf16) + epilogue ----------------
// BM = MF*32, BK=64, DEPTH=2 dbuf. T2 swizzle via pre-swizzled global source (rule 21).
// RES: 0 none, 1 f32, 2 bf16. OUTM: 0 bf16, 1 f32, 2 f32+bf16 copy.
// QKV (requires MF=4): LDS-staged coalesced split epilogue -> Q rows / kp chunks / vt runs.
template<int MF, int RES, bool ADD_POS, bool LEAKY, int OUTM, bool QKV>
__global__ __launch_bounds__(256)
void gemm_bt(const short* __restrict__ A, const short* __restrict__ Bt,
             const float* __restrict__ bias, const float* __restrict__ pos,
             const void* __restrict__ res, void* __restrict__ Cout,
             short* __restrict__ aux_kp, short* __restrict__ aux_vt,
             int N, int K)
{
    __shared__ short lds[2 * MF * 32 * 64 + 2 * 128 * 64];
    short* As = lds;
    short* Bs = lds + 2 * MF * 32 * 64;
    int bx = blockIdx.x, by = blockIdx.y;
    xcd_remap(bx, by);
    const int t    = threadIdx.x;
    const int lane = t & 63;
    const int w    = t >> 6;
    const int m0   = by * (MF * 32);
    const int n0   = bx * 128;
    const int wm   = (w >> 1) * (MF * 16);
    const int wn   = (w & 1) * 64;

    floatx4 acc[MF][4];
#pragma unroll
    for (int i = 0; i < MF; ++i)
#pragma unroll
        for (int j = 0; j < 4; ++j)
            acc[i][j] = (floatx4){0.f, 0.f, 0.f, 0.f};

    const int srow = t >> 3;
    const int sch  = t & 7;
    const short* Ag = A  + (size_t)m0 * K;
    const short* Bg = Bt + (size_t)n0 * K;

#define STAGE(buf, k0)                                                              \
    {                                                                               \
        _Pragma("unroll")                                                           \
        for (int i = 0; i < MF; ++i) {                                              \
            int row = srow + i * 32;                                                \
            GLDS16(Ag + (size_t)row * K + (k0) + ((sch ^ (row & 7)) << 3),          \
                   &As[(buf) * (MF * 2048) + (size_t)(t + i * 256) * 8]);           \
        }                                                                           \
        _Pragma("unroll")                                                           \
        for (int i = 0; i < 4; ++i) {                                               \
            int row = srow + i * 32;                                                \
            GLDS16(Bg + (size_t)row * K + (k0) + ((sch ^ (row & 7)) << 3),          \
                   &Bs[(buf) * 8192 + (size_t)(t + i * 256) * 8]);                  \
        }                                                                           \
    }

    STAGE(0, 0);
    __syncthreads();
    int cur = 0;
    for (int k0 = 0; k0 < K; k0 += 64) {
        if (k0 + 64 < K) STAGE(cur ^ 1, k0 + 64);
#pragma unroll
        for (int ks = 0; ks < 2; ++ks) {
            short8 af[MF], bf[4];
#pragma unroll
            for (int i = 0; i < MF; ++i) {
                int row = wm + i * 16 + (lane & 15);
                int ch  = (ks * 4 + (lane >> 4)) ^ (row & 7);
                af[i] = *(const short8*)&As[cur * (MF * 2048) + row * 64 + ch * 8];
            }
#pragma unroll
            for (int j = 0; j < 4; ++j) {
                int row = wn + j * 16 + (lane & 15);
                int ch  = (ks * 4 + (lane >> 4)) ^ (row & 7);
                bf[j] = *(const short8*)&Bs[cur * 8192 + row * 64 + ch * 8];
            }
#pragma unroll
            for (int i = 0; i < MF; ++i)
#pragma unroll
                for (int j = 0; j < 4; ++j)
                    acc[i][j] = __builtin_amdgcn_mfma_f32_16x16x32_bf16(af[i], bf[j], acc[i][j], 0, 0, 0);
        }
        __syncthreads();
        cur ^= 1;
    }
#undef STAGE

    if constexpr (QKV) {
        // ---- LDS-staged coalesced split epilogue (tile is 128x128; type per block) ----
        short* T = lds;                    // 128 x 130 bf16, LDS free after loop
        const int type = bx / 6;           // 0=Q, 1=K, 2=V
#pragma unroll
        for (int i = 0; i < MF; ++i)
#pragma unroll
            for (int j = 0; j < 4; ++j)
#pragma unroll
                for (int r = 0; r < 4; ++r) {
                    const int rowl = wm + i * 16 + (lane >> 4) * 4 + r;
                    const int coll = wn + (lane & 15) + j * 16;
                    const short sv16 = f2b(acc[i][j][r] + bias[n0 + coll]);
                    if (type == 2) T[coll * 130 + rowl] = sv16;   // V stored transposed
                    else           T[rowl * 130 + coll] = sv16;
                }
        __syncthreads();
        if (type == 0) {
#pragma unroll
            for (int p = 0; p < 8; ++p) {
                int flat = p * 2048 + t * 8;
                int row = flat >> 7, c = flat & 127;
                *(short8*)&((short*)Cout)[(size_t)(m0 + row) * 768 + n0 + c] =
                    *(const short8*)&T[row * 130 + c];
            }
        } else if (type == 1) {
            const int hbase = (n0 - 768) >> 6;
#pragma unroll
            for (int p = 0; p < 8; ++p) {
                int q = p * 256 + t;
                int l = q >> 4, hh = (q >> 3) & 1, cc = q & 7;
                int g = m0 + l, b = g / 576, lg = g - b * 576;
                int scc = cc ^ (l & 7);
                *(short8*)&aux_kp[(((size_t)b * 12 + hbase + hh) * 576 + lg) * 64 + cc * 8] =
                    *(const short8*)&T[l * 130 + hh * 64 + scc * 8];
            }
        } else {
            const int hbase = (n0 - 1536) >> 6;
#pragma unroll
            for (int p = 0; p < 8; ++p) {
                int q = p * 256 + t;
                int coll = q >> 4, lc = (q >> 3) & 1, cc = q & 7;
                int hh = coll >> 6, dd = coll & 63;
                int gb = m0 + lc * 64, b = gb / 576, lgb = gb - b * 576;
                int scc = cc ^ (dd & 7);
                *(short8*)&aux_vt[(((size_t)b * 12 + hbase + hh) * 64 + dd) * 576 + lgb + cc * 8] =
                    *(const short8*)&T[coll * 130 + lc * 64 + scc * 8];
            }
        }
        return;
    }

    const int colb = n0 + wn + (lane & 15);
    const int rowb = m0 + wm + ((lane >> 4) * 4);
#pragma unroll
    for (int i = 0; i < MF; ++i) {
#pragma unroll
        for (int j = 0; j < 4; ++j) {
            const int col = colb + j * 16;
            const float bv = bias[col];
#pragma unroll
            for (int r = 0; r < 4; ++r) {
                const int row = rowb + i * 16 + r;
                float v = acc[i][j][r] + bv;
                if constexpr (ADD_POS) v += pos[(size_t)(row % LSEQ) * N + col];
                if constexpr (RES == 1) v += ((const float*)res)[(size_t)row * N + col];
                if constexpr (RES == 2) v += b2f(((const short*)res)[(size_t)row * N + col]);
                if constexpr (LEAKY)   v = v >= 0.f ? v : 0.01f * v;
                if constexpr (OUTM == 1) {
                    ((float*)Cout)[(size_t)row * N + col] = v;
                } else if constexpr (OUTM == 2) {
                    ((float*)Cout)[(size_t)row * N + col] = v;
                    aux_kp[(size_t)row * N + col] = f2b(v);
                } else {
                    ((short*)Cout)[(size_t)row * N + col] = f2b(v);
                }
            }
        }
    }
}

// ---------------- split-K x2 GEMM, 128x128 tile, BK=64, DEPTH=2 (64 KB LDS, 2 blocks/CU) ------
__global__ __launch_bounds__(256)
void gemm_sk2(const short* __restrict__ A, const short* __restrict__ Bt,
              float* __restrict__ P0, float* __restrict__ P1, int N, int K)
{
    __shared__ short As[2 * 128 * 64];
    __shared__ short Bs[2 * 128 * 64];
    int bx = blockIdx.x, by = blockIdx.y;
    xcd_remap(bx, by);
    const int t    = threadIdx.x;
    const int lane = t & 63;
    const int w    = t >> 6;
    const int m0   = by * 128;
    const int n0   = bx * 128;
    const int wm   = (w >> 1) * 64;
    const int wn   = (w & 1) * 64;
    const int klen  = K >> 1;
    const int kbase = blockIdx.z * klen;

    floatx4 acc[4][4];
#pragma unroll
    for (int i = 0; i < 4; ++i)
#pragma unroll
        for (int j = 0; j < 4; ++j)
            acc[i][j] = (floatx4){0.f, 0.f, 0.f, 0.f};

    const int srow = t >> 3;
    const int sch  = t & 7;
    const short* Ag = A  + (size_t)m0 * K + kbase;
    const short* Bg = Bt + (size_t)n0 * K + kbase;

#define STAGE(buf, k0)                                                              \
    {                                                                               \
        _Pragma("unroll")                                                           \
        for (int i = 0; i < 4; ++i) {                                               \
            int row = srow + i * 32;                                                \
            GLDS16(Ag + (size_t)row * K + (k0) + ((sch ^ (row & 7)) << 3),          \
                   &As[(buf) * 8192 + (size_t)(t + i * 256) * 8]);                  \
        }                                                                           \
        _Pragma("unroll")                                                           \
        for (int i = 0; i < 4; ++i) {                                               \
            int row = srow + i * 32;                                                \
            GLDS16(Bg + (size_t)row * K + (k0) + ((sch ^ (row & 7)) << 3),          \
                   &Bs[(buf) * 8192 + (size_t)(t + i * 256) * 8]);                  \
        }                                                                           \
    }

    STAGE(0, 0);
    __syncthreads();
    int cur = 0;
    for (int k0 = 0; k0 < klen; k0 += 64) {
        if (k0 + 64 < klen) STAGE(cur ^ 1, k0 + 64);
#pragma unroll
        for (int ks = 0; ks < 2; ++ks) {
            short8 af[4], bf[4];
#pragma unroll
            for (int i = 0; i < 4; ++i) {
                int row = wm + i * 16 + (lane & 15);
                int ch  = (ks * 4 + (lane >> 4)) ^ (row & 7);
                af[i] = *(const short8*)&As[cur * 8192 + row * 64 + ch * 8];
            }
#pragma unroll
            for (int j = 0; j < 4; ++j) {
                int row = wn + j * 16 + (lane & 15);
                int ch  = (ks * 4 + (lane >> 4)) ^ (row & 7);
                bf[j] = *(const short8*)&Bs[cur * 8192 + row * 64 + ch * 8];
            }
#pragma unroll
            for (int i = 0; i < 4; ++i)
#pragma unroll
                for (int j = 0; j < 4; ++j)
                    acc[i][j] = __builtin_amdgcn_mfma_f32_16x16x32_bf16(af[i], bf[j], acc[i][j], 0, 0, 0);
        }
        __syncthreads();
        cur ^= 1;
    }
#undef STAGE

    float* P = blockIdx.z ? P1 : P0;
    const int colb = n0 + wn + (lane & 15);
    const int rowb = m0 + wm + ((lane >> 4) * 4);
#pragma unroll
    for (int i = 0; i < 4; ++i)
#pragma unroll
        for (int j = 0; j < 4; ++j)
#pragma unroll
            for (int r = 0; r < 4; ++r)
                P[(size_t)(rowb + i * 16 + r) * N + colb + j * 16] = acc[i][j][r];
}

// ---------------- split-K combine + epilogue + FUSED LayerNorm (row-per-wave) ----------------
template<int RES, bool ADD_POS, int LNMODE>
__global__ __launch_bounds__(256)
void combineln(const float* __restrict__ P0, const float* __restrict__ P1,
               const float* __restrict__ bias, const float* __restrict__ pos,
               const void* __restrict__ res,
               const float* __restrict__ g, const float* __restrict__ lb,
               float* __restrict__ hout, short* __restrict__ bout)
{
    const int w = threadIdx.x >> 6, lane = threadIdx.x & 63;
    const int row = blockIdx.x * 4 + w;
    const size_t base = (size_t)row * 768;
    float v[3][4];
    float s = 0.f, ss = 0.f;
#pragma unroll
    for (int q = 0; q < 3; ++q) {
        const int col = q * 256 + lane * 4;
        floatx4 a  = *(const floatx4*)&P0[base + col];
        floatx4 b  = *(const floatx4*)&P1[base + col];
        floatx4 bv = *(const floatx4*)&bias[col];
        floatx4 t;
#pragma unroll
        for (int j = 0; j < 4; ++j) t[j] = a[j] + b[j] + bv[j];
        if constexpr (ADD_POS) {
            floatx4 p = *(const floatx4*)&pos[(size_t)(row % LSEQ) * 768 + col];
#pragma unroll
            for (int j = 0; j < 4; ++j) t[j] += p[j];
        }
        if constexpr (RES == 1) {
            floatx4 rr = *(const floatx4*)&((const float*)res)[base + col];
#pragma unroll
            for (int j = 0; j < 4; ++j) t[j] += rr[j];
        }
        if constexpr (RES == 2) {
            short4v rr = *(const short4v*)&((const short*)res)[base + col];
#pragma unroll
            for (int j = 0; j < 4; ++j) t[j] += b2f(rr[j]);
        }
#pragma unroll
        for (int j = 0; j < 4; ++j) { v[q][j] = t[j]; s += t[j]; ss += t[j] * t[j]; }
        *(floatx4*)&hout[base + col] = t;
    }
#pragma unroll
    for (int m = 1; m < 64; m <<= 1) {
        s  += __shfl_xor(s, m, 64);
        ss += __shfl_xor(ss, m, 64);
    }
    const float mean = s * (1.f / 768.f);
    const float var  = ss * (1.f / 768.f) - mean * mean;
    const float rstd = rsqrtf(var + 1e-5f);
#pragma unroll
    for (int q = 0; q < 3; ++q) {
        const int col = q * 256 + lane * 4;
        short4v ob;
        if constexpr (LNMODE == 1) {
            floatx4 gv = *(const floatx4*)&g[col];
            floatx4 bv = *(const floatx4*)&lb[col];
#pragma unroll
            for (int j = 0; j < 4; ++j) ob[j] = f2b((v[q][j] - mean) * rstd * gv[j] + bv[j]);
        } else {
#pragma unroll
            for (int j = 0; j < 4; ++j) ob[j] = f2b(v[q][j]);
        }
        *(short4v*)&bout[base + col] = ob;
    }
}

// ---------------- element-wise split-K combine (proj; no LN) ----------------
template<int RES, bool ADD_POS, int OUTM>
__global__ __launch_bounds__(256)
void combinek(const float* __restrict__ P0, const float* __restrict__ P1,
              const float* __restrict__ bias, const float* __restrict__ pos,
              const void* __restrict__ res, float* __restrict__ out,
              short* __restrict__ auxb)
{
    const size_t i4 = ((size_t)blockIdx.x * 256 + threadIdx.x) * 4;
    const int row = (int)(i4 / 768);
    const int col = (int)(i4 % 768);
    floatx4 a = *(const floatx4*)&P0[i4];
    floatx4 b = *(const floatx4*)&P1[i4];
    floatx4 bv = *(const floatx4*)&bias[col];
    floatx4 v;
#pragma unroll
    for (int j = 0; j < 4; ++j) v[j] = a[j] + b[j] + bv[j];
    if constexpr (ADD_POS) {
        floatx4 p = *(const floatx4*)&pos[(size_t)(row % LSEQ) * 768 + col];
#pragma unroll
        for (int j = 0; j < 4; ++j) v[j] += p[j];
    }
    if constexpr (RES == 1) {
        floatx4 rr = *(const floatx4*)&((const float*)res)[i4];
#pragma unroll
        for (int j = 0; j < 4; ++j) v[j] += rr[j];
    }
    if constexpr (RES == 2) {
        short4v rr = *(const short4v*)&((const short*)res)[i4];
#pragma unroll
        for (int j = 0; j < 4; ++j) v[j] += b2f(rr[j]);
    }
    *(floatx4*)&out[i4] = v;
    if constexpr (OUTM == 2) {
        short4v ob;
#pragma unroll
        for (int j = 0; j < 4; ++j) ob[j] = f2b(v[j]);
        *(short4v*)&auxb[i4] = ob;
    }
}

// ---------------- MFMA flash attention, 128-key double tiles. grid (9, 96), 4 waves -----------
// Two 64-key tiles per barrier pair: one softmax pass over 128 keys (shfl chains + barriers
// amortized 2x per key). LDS ~50 KB -> 3 blocks/CU.
__global__ __launch_bounds__(256)
void attn_mfma(const short* __restrict__ qbuf, const short* __restrict__ kp,
               const short* __restrict__ vt, short* __restrict__ oout, int causal)
{
    const int qt = blockIdx.x, bh = blockIdx.y;
    const int b = bh / 12, h = bh % 12;
    const int t = threadIdx.x, lane = t & 63, w = t >> 6;

    __shared__ short Ks[2][64 * 64];
    __shared__ short Vs[2][64 * 64];
    __shared__ short Plds[4][16][136];

    const int nrow = lane & 15;
    const int kch  = (lane >> 4) * 8;
    const int swz  = (lane & 7) << 3;

    short8 aq[2];
    {
        const short* qrow = qbuf + ((size_t)(b * LSEQ) + qt * 64 + w * 16 + nrow) * 768 + h * 64 + kch;
        aq[0] = *(const short8*)qrow;
        aq[1] = *(const short8*)(qrow + 32);
    }

    float m[4], lsum[4];
    floatx4 oacc[4];
#pragma unroll
    for (int r = 0; r < 4; ++r) { m[r] = -3e38f; lsum[r] = 0.f; }
#pragma unroll
    for (int j = 0; j < 4; ++j) oacc[j] = (floatx4){0.f, 0.f, 0.f, 0.f};

    const int ktend = causal ? qt : 8;
    const short* ksrc = kp + ((size_t)bh * LSEQ) * 64;
    const short* vsrc = vt + ((size_t)bh * 64) * LSEQ;

#define STAGE_KV(buf, kt)                                                             \
    {                                                                                 \
        const short* kt_src = ksrc + (size_t)((kt) * 64) * 64;                        \
        GLDS16(kt_src + (size_t)t * 8,         &Ks[buf][(size_t)t * 8]);              \
        GLDS16(kt_src + (size_t)(t + 256) * 8, &Ks[buf][(size_t)(t + 256) * 8]);      \
        GLDS16(vsrc + (size_t)(t >> 3) * LSEQ + (kt) * 64 + (t & 7) * 8,              \
               &Vs[buf][(size_t)t * 8]);                                              \
        GLDS16(vsrc + (size_t)((t + 256) >> 3) * LSEQ + (kt) * 64 + (t & 7) * 8,      \
               &Vs[buf][(size_t)(t + 256) * 8]);                                      \
    }

    for (int kt2 = 0; kt2 <= ktend; kt2 += 2) {
        const int two = (kt2 + 1 <= ktend) ? 1 : 0;
        __syncthreads();
        STAGE_KV(0, kt2);
        if (two) STAGE_KV(1, kt2 + 1);
        __syncthreads();

        floatx4 sc[8];
#pragma unroll
        for (int j = 0; j < 8; ++j) sc[j] = (floatx4){0.f, 0.f, 0.f, 0.f};
        for (int half = 0; half <= two; ++half) {
#pragma unroll
            for (int s = 0; s < 2; ++s)
#pragma unroll
                for (int j = 0; j < 4; ++j) {
                    short8 bk = *(const short8*)&Ks[half][(16 * j + nrow) * 64 + ((kch + 32 * s) ^ swz)];
                    sc[half * 4 + j] = __builtin_amdgcn_mfma_f32_16x16x32_bf16(aq[s], bk, sc[half * 4 + j], 0, 0, 0);
                }
        }
        float sv[8][4];
#pragma unroll
        for (int jj = 0; jj < 8; ++jj)
#pragma unroll
            for (int r = 0; r < 4; ++r) {
                float v;
                if ((jj >> 2) <= two) {
                    v = sc[jj][r] * 0.125f;
                    const int kt = kt2 + (jj >> 2);
                    if (causal && kt == qt) {
                        int key = kt * 64 + 16 * (jj & 3) + nrow;
                        int qr  = qt * 64 + w * 16 + (lane >> 4) * 4 + r;
                        if (key > qr) v = -1e12f;
                    }
                } else {
                    v = -3e38f;     // tail filler: exp -> 0
                }
                sv[jj][r] = v;
            }
#pragma unroll
        for (int r = 0; r < 4; ++r) {
            float tm = sv[0][r];
#pragma unroll
            for (int jj = 1; jj < 8; ++jj) tm = fmaxf(tm, sv[jj][r]);
            tm = fmaxf(tm, __shfl_xor(tm, 1, 64));
            tm = fmaxf(tm, __shfl_xor(tm, 2, 64));
            tm = fmaxf(tm, __shfl_xor(tm, 4, 64));
            tm = fmaxf(tm, __shfl_xor(tm, 8, 64));
            float nm = fmaxf(m[r], tm);
            float c  = __expf(m[r] - nm);
            m[r] = nm;
            float ps = 0.f;
#pragma unroll
            for (int jj = 0; jj < 8; ++jj) {
                float p = __expf(sv[jj][r] - nm);
                sv[jj][r] = p;
                ps += p;
            }
            lsum[r] = lsum[r] * c + ps;
#pragma unroll
            for (int j = 0; j < 4; ++j) oacc[j][r] *= c;
        }
#pragma unroll
        for (int jj = 0; jj < 8; ++jj)
#pragma unroll
            for (int r = 0; r < 4; ++r)
                Plds[w][(lane >> 4) * 4 + r][(jj >> 2) * 64 + 16 * (jj & 3) + nrow] = f2b(sv[jj][r]);
        for (int half = 0; half <= two; ++half) {
            short8 ap[2];
#pragma unroll
            for (int s = 0; s < 2; ++s)
                ap[s] = *(const short8*)&Plds[w][nrow][half * 64 + kch + 32 * s];
#pragma unroll
            for (int s = 0; s < 2; ++s)
#pragma unroll
                for (int j = 0; j < 4; ++j) {
                    short8 bv = *(const short8*)&Vs[half][(16 * j + nrow) * 64 + ((kch + 32 * s) ^ swz)];
                    oacc[j] = __builtin_amdgcn_mfma_f32_16x16x32_bf16(ap[s], bv, oacc[j], 0, 0, 0);
                }
        }
    }
#undef STAGE_KV

    float inv[4];
#pragma unroll
    for (int r = 0; r < 4; ++r) {
        float L = lsum[r];
        L += __shfl_xor(L, 1, 64);
        L += __shfl_xor(L, 2, 64);
        L += __shfl_xor(L, 4, 64);
        L += __shfl_xor(L, 8, 64);
        inv[r] = 1.f / L;
    }
#pragma unroll
    for (int j = 0; j < 4; ++j)
#pragma unroll
        for (int r = 0; r < 4; ++r) {
            size_t lq = (size_t)qt * 64 + w * 16 + (lane >> 4) * 4 + r;
            oout[((size_t)bh * LSEQ + lq) * 64 + 16 * j + nrow] = f2b(oacc[j][r] * inv[r]);
        }
}

// ---------------- transposes ----------------
__global__ void transpose_f2b(const float* __restrict__ in, short* __restrict__ out,
                              int R, int C, long long ibs, long long obs)
{
    __shared__ float tile[32][33];
    const int b = blockIdx.z;
    const float* inb = in + (long long)b * ibs;
    short* outb = out + (long long)b * obs;
    const int r0 = blockIdx.y * 32, c0 = blockIdx.x * 32;
    const int tx = threadIdx.x, ty = threadIdx.y;
#pragma unroll
    for (int i = 0; i < 32; i += 8) tile[ty + i][tx] = inb[(size_t)(r0 + ty + i) * C + c0 + tx];
    __syncthreads();
#pragma unroll
    for (int i = 0; i < 32; i += 8) outb[(size_t)(c0 + ty + i) * R + r0 + tx] = f2b(tile[tx][ty + i]);
}

__global__ void transpose_f2f(const float* __restrict__ in, float* __restrict__ out,
                              int R, int C, long long ibs, long long obs)
{
    __shared__ float tile[32][33];
    const int b = blockIdx.z;
    const float* inb = in + (long long)b * ibs;
    float* outb = out + (long long)b * obs;
    const int r0 = blockIdx.y * 32, c0 = blockIdx.x * 32;
    const int tx = threadIdx.x, ty = threadIdx.y;
#pragma unroll
    for (int i = 0; i < 32; i += 8) tile[ty + i][tx] = inb[(size_t)(r0 + ty + i) * C + c0 + tx];
    __syncthreads();
#pragma unroll
    for (int i = 0; i < 32; i += 8) outb[(size_t)(c0 + ty + i) * R + r0 + tx] = tile[tx][ty + i];
}

// ---------------- misc small kernels ----------------
__global__ void concat_qkv_bias(const float* __restrict__ bq, const float* __restrict__ bk,
                                const float* __restrict__ bv, float* __restrict__ out)
{
    int i = blockIdx.x * 256 + threadIdx.x;
    int layer = i / 2304, j = i % 2304;
    float v;
    if (j < 768)       v = bq[layer * 768 + j];
    else if (j < 1536) v = bk[layer * 768 + j - 768];
    else               v = bv[layer * 768 + j - 1536];
    out[i] = v;
}

__global__ void im2col_kernel(const float* __restrict__ x, short* __restrict__ xcol)
{
    const size_t idx = (size_t)blockIdx.x * 256 + threadIdx.x;
    const int k = (int)(idx % 768);
    const size_t m = idx / 768;
    const int c  = k >> 8;
    const int ky = (k >> 4) & 15;
    const int kx = k & 15;
    const int b  = (int)(m / 576);
    const int l  = (int)(m % 576);
    const int ph = l / 24, pw = l % 24;
    xcol[idx] = f2b(x[((size_t)(b * 3 + c) * 384 + ph * 16 + ky) * 384 + pw * 16 + kx]);
}

__global__ void cast_f32_b16(const float* __restrict__ in, short* __restrict__ out, int n)
{
    int i = blockIdx.x * 256 + threadIdx.x;
    if (i < n) out[i] = f2b(in[i]);
}

// ---------------- host launcher ----------------
extern "C" void kernel_launch(void* const* d_in, const int* in_sizes, int n_in,
                              void* d_out, int out_size, void* d_ws, size_t ws_size,
                              hipStream_t stream)
{
    const float* x      = (const float*)d_in[0];
    const float* conv_w = (const float*)d_in[1];
    const float* conv_b = (const float*)d_in[2];
    const float* pos    = (const float*)d_in[3];
    const float* ln0_s  = (const float*)d_in[4];
    const float* ln0_b  = (const float*)d_in[5];
    const float* Wq     = (const float*)d_in[6];
    const float* bq     = (const float*)d_in[7];
    const float* Wk     = (const float*)d_in[8];
    const float* bk     = (const float*)d_in[9];
    const float* Wv     = (const float*)d_in[10];
    const float* bv     = (const float*)d_in[11];
    const float* Wo     = (const float*)d_in[12];
    const float* bo     = (const float*)d_in[13];
    const float* ln1_s  = (const float*)d_in[14];
    const float* ln1_b  = (const float*)d_in[15];
    const float* W1     = (const float*)d_in[16];
    const float* b1     = (const float*)d_in[17];
    const float* W2     = (const float*)d_in[18];
    const float* b2     = (const float*)d_in[19];
    const float* proj_w = (const float*)d_in[20];
    const float* proj_b = (const float*)d_in[21];

    char* ws = (char*)d_ws;
    short* qkvT  = (short*)(ws);                    // [8][2304][768] bf16
    short* woT   = (short*)(ws + 28311552);         // [8][768][768]
    short* w1T   = (short*)(ws + 37748736);         // [8][3072][768]
    short* w2T   = (short*)(ws + 75497472);         // [8][768][3072]
    short* projT = (short*)(ws + 113246208);        // [768][768]
    float* qkvb  = (float*)(ws + 114425856);        // [8][2304] f32
    short* tmpA  = (short*)(ws + 114499584);        // xcol / m1 bf16; kp/vt overlay; Wo/proj partials
    float* h     = (float*)(ws + 142811136);        // residual f32 / conv-P0 / W2-P0 / final yf
    short* xn    = (short*)(ws + 156966912);        // LN0 out bf16 / hb at end
    short* xrb   = (short*)(ws + 164044800);        // LN1 out bf16
    short* qbuf  = (short*)(ws + 185278464);        // Q bf16 / f32 P1 overlay (conv, W2)
    short* o     = (short*)(ws + 206512128);        // attn out (scrambled) bf16
    short* convB = (short*)(ws + 213590016);        // conv_w cast bf16 [768][768]

    short* kp = tmpA;                               // [96][576][64] bf16 (overlay)
    short* vt = tmpA + 3538944;                     // [96][64][576] bf16
    float* tmpAF  = (float*)tmpA;                   // partial P0 (Wo, proj)
    float* tmpAF2 = tmpAF + 3538944;                // partial P1 (Wo, proj)
    float* qbufF  = (float*)qbuf;                   // partial P1 (conv, W2)

    dim3 tb(32, 8);
    transpose_f2b<<<dim3(24, 24, 8), tb, 0, stream>>>(Wq, qkvT,           768, 768, 589824, 1769472);
    transpose_f2b<<<dim3(24, 24, 8), tb, 0, stream>>>(Wk, qkvT + 589824,  768, 768, 589824, 1769472);
    transpose_f2b<<<dim3(24, 24, 8), tb, 0, stream>>>(Wv, qkvT + 1179648, 768, 768, 589824, 1769472);
    transpose_f2b<<<dim3(24, 24, 8), tb, 0, stream>>>(Wo, woT,            768, 768, 589824, 589824);
    transpose_f2b<<<dim3(96, 24, 8), tb, 0, stream>>>(W1, w1T,            768, 3072, 2359296, 2359296);
    transpose_f2b<<<dim3(24, 96, 8), tb, 0, stream>>>(W2, w2T,            3072, 768, 2359296, 2359296);
    transpose_f2b<<<dim3(24, 24, 1), tb, 0, stream>>>(proj_w, projT,      768, 768, 0, 0);
    cast_f32_b16<<<2304, 256, 0, stream>>>(conv_w, convB, 589824);
    concat_qkv_bias<<<72, 256, 0, stream>>>(bq, bk, bv, qkvb);

    // patch embed: im2col + split-K conv GEMM + combine(+pos, fused LN0[0]) -> h, xn
    im2col_kernel<<<13824, 256, 0, stream>>>(x, tmpA);
    gemm_sk2<<<dim3(6, 36, 2), 256, 0, stream>>>(tmpA, convB, h, qbufF, 768, 768);
    combineln<0, true, 1><<<1152, 256, 0, stream>>>(
        h, qbufF, conv_b, pos, nullptr, ln0_s, ln0_b, h, xn);

    for (int i = 0; i < NLAYERS; ++i) {
        // qkv GEMM (128^2 tile, LDS-coalesced split epilogue): Q->qbuf, K->kp, V->vt
        gemm_bt<4, 0, false, false, 0, true><<<dim3(18, 36), 256, 0, stream>>>(
            xn, qkvT + (size_t)i * 1769472, qkvb + i * 2304, nullptr, nullptr, qbuf, kp, vt, 2304, 768);
        attn_mfma<<<dim3(9, 96), 256, 0, stream>>>(qbuf, kp, vt, o, i == 0 ? 1 : 0);
        // Wo: split-K (P0/P1 in tmpA, kp/vt dead) + combine(+f32 h residual, fused LN1) -> h, xrb
        gemm_sk2<<<dim3(6, 36, 2), 256, 0, stream>>>(
            o, woT + (size_t)i * 589824, tmpAF, tmpAF2, 768, 768);
        combineln<1, false, 1><<<1152, 256, 0, stream>>>(
            tmpAF, tmpAF2, bo + i * 768, nullptr, h, ln1_s + i * 768, ln1_b + i * 768, h, xrb);
        // W1 (leaky, 128^2 tile) -> tmpA (clobbers Wo partials, dead)
        gemm_bt<4, 0, false, true, 0, false><<<dim3(24, 36), 256, 0, stream>>>(
            xrb, w1T + (size_t)i * 2359296, b1 + i * 3072, nullptr, nullptr, tmpA, nullptr, nullptr, 3072, 768);
        // W2: split-K (P0=h dead, P1=qbuf dead) + combine(+bf16 xrb residual, fused LN0[i+1])
        gemm_sk2<<<dim3(6, 36, 2), 256, 0, stream>>>(
            tmpA, w2T + (size_t)i * 2359296, h, qbufF, 768, 3072);
        if (i < NLAYERS - 1) {
            combineln<2, false, 1><<<1152, 256, 0, stream>>>(
                h, qbufF, b2 + i * 768, nullptr, xrb, ln0_s + (i + 1) * 768, ln0_b + (i + 1) * 768, h, xn);
        } else {
            combineln<2, false, 0><<<1152, 256, 0, stream>>>(
                h, qbufF, b2 + i * 768, nullptr, xrb, nullptr, nullptr, h, xn);
        }
    }

    // final projection (split-K into tmpA, m1 dead) + combine -> h(f32), then output scramble
    short* hb = xn;
    gemm_sk2<<<dim3(6, 36, 2), 256, 0, stream>>>(hb, projT, tmpAF, tmpAF2, 768, 768);
    combinek<0, false, 1><<<3456, 256, 0, stream>>>(
        tmpAF, tmpAF2, proj_b, nullptr, nullptr, h, nullptr);
    transpose_f2f<<<dim3(24, 18, 8), tb, 0, stream>>>(h, (float*)d_out, 576, 768, 442368, 442368);
}

// Round 21
// 1515.656 us; speedup vs baseline: 1.0484x; 1.0484x over previous
//
#include <hip/hip_runtime.h>
#include <hip/hip_bf16.h>
#include <stdint.h>

#define NLAYERS 8
#define LSEQ 576
#define EMB 768
#define NHEAD 12
#define HDIM 64
#define FFDIM 3072
#define BLROWS 4608   // B*L

typedef __attribute__((ext_vector_type(8))) short short8;
typedef __attribute__((ext_vector_type(4))) short short4v;
typedef __attribute__((ext_vector_type(4))) float floatx4;

__device__ __forceinline__ float b2f(short s) {
    union { float f; uint32_t u; } x; x.u = ((uint32_t)(uint16_t)s) << 16; return x.f;
}
__device__ __forceinline__ short f2b(float f) {
    union { float f; uint32_t u; } x; x.f = f;
    uint32_t r = x.u + 0x7fffu + ((x.u >> 16) & 1u);
    return (short)(r >> 16);
}

#define GLDS16(gp, lp) __builtin_amdgcn_global_load_lds( \
    (const __attribute__((address_space(1))) void*)(gp), \
    (__attribute__((address_space(3))) void*)(lp), 16, 0, 0)

// bijective XCD-chunked remap (m204)
__device__ __forceinline__ void xcd_remap(int& bx, int& by) {
    const int gx = gridDim.x;
    const int n  = gx * gridDim.y;
    const int orig = by * gx + bx;
    const int q = n >> 3, r = n & 7;
    const int xcd = orig & 7;
    const int wgid = (xcd < r ? xcd * (q + 1) : r * (q + 1) + (xcd - r) * q) + (orig >> 3);
    bx = wgid % gx;
    by = wgid / gx;
}

// ---------------- GEMM: C[M,N] = A[M,K](bf16) * Bt[N,K]^T (bf16) + epilogue ----------------
// BM = MF*32, BK=64, DEPTH=2 dbuf. T2 swizzle via pre-swizzled global source (rule 21).
// RES: 0 none, 1 f32, 2 bf16. OUTM: 0 bf16, 1 f32, 2 f32+bf16 copy.
// QKV (requires MF=4): LDS-staged coalesced split epilogue -> Q rows / kp chunks / vt runs.
template<int MF, int RES, bool ADD_POS, bool LEAKY, int OUTM, bool QKV>
__global__ __launch_bounds__(256)
void gemm_bt(const short* __restrict__ A, const short* __restrict__ Bt,
             const float* __restrict__ bias, const float* __restrict__ pos,
             const void* __restrict__ res, void* __restrict__ Cout,
             short* __restrict__ aux_kp, short* __restrict__ aux_vt,
             int N, int K)
{
    __shared__ short lds[2 * MF * 32 * 64 + 2 * 128 * 64];
    short* As = lds;
    short* Bs = lds + 2 * MF * 32 * 64;
    int bx = blockIdx.x, by = blockIdx.y;
    xcd_remap(bx, by);
    const int t    = threadIdx.x;
    const int lane = t & 63;
    const int w    = t >> 6;
    const int m0   = by * (MF * 32);
    const int n0   = bx * 128;
    const int wm   = (w >> 1) * (MF * 16);
    const int wn   = (w & 1) * 64;

    floatx4 acc[MF][4];
#pragma unroll
    for (int i = 0; i < MF; ++i)
#pragma unroll
        for (int j = 0; j < 4; ++j)
            acc[i][j] = (floatx4){0.f, 0.f, 0.f, 0.f};

    const int srow = t >> 3;
    const int sch  = t & 7;
    const short* Ag = A  + (size_t)m0 * K;
    const short* Bg = Bt + (size_t)n0 * K;

#define STAGE(buf, k0)                                                              \
    {                                                                               \
        _Pragma("unroll")                                                           \
        for (int i = 0; i < MF; ++i) {                                              \
            int row = srow + i * 32;                                                \
            GLDS16(Ag + (size_t)row * K + (k0) + ((sch ^ (row & 7)) << 3),          \
                   &As[(buf) * (MF * 2048) + (size_t)(t + i * 256) * 8]);           \
        }                                                                           \
        _Pragma("unroll")                                                           \
        for (int i = 0; i < 4; ++i) {                                               \
            int row = srow + i * 32;                                                \
            GLDS16(Bg + (size_t)row * K + (k0) + ((sch ^ (row & 7)) << 3),          \
                   &Bs[(buf) * 8192 + (size_t)(t + i * 256) * 8]);                  \
        }                                                                           \
    }

    STAGE(0, 0);
    __syncthreads();
    int cur = 0;
    for (int k0 = 0; k0 < K; k0 += 64) {
        if (k0 + 64 < K) STAGE(cur ^ 1, k0 + 64);
#pragma unroll
        for (int ks = 0; ks < 2; ++ks) {
            short8 af[MF], bf[4];
#pragma unroll
            for (int i = 0; i < MF; ++i) {
                int row = wm + i * 16 + (lane & 15);
                int ch  = (ks * 4 + (lane >> 4)) ^ (row & 7);
                af[i] = *(const short8*)&As[cur * (MF * 2048) + row * 64 + ch * 8];
            }
#pragma unroll
            for (int j = 0; j < 4; ++j) {
                int row = wn + j * 16 + (lane & 15);
                int ch  = (ks * 4 + (lane >> 4)) ^ (row & 7);
                bf[j] = *(const short8*)&Bs[cur * 8192 + row * 64 + ch * 8];
            }
#pragma unroll
            for (int i = 0; i < MF; ++i)
#pragma unroll
                for (int j = 0; j < 4; ++j)
                    acc[i][j] = __builtin_amdgcn_mfma_f32_16x16x32_bf16(af[i], bf[j], acc[i][j], 0, 0, 0);
        }
        __syncthreads();
        cur ^= 1;
    }
#undef STAGE

    if constexpr (QKV) {
        // ---- LDS-staged coalesced split epilogue (tile is 128x128; type per block) ----
        short* T = lds;                    // 128 x 130 bf16, LDS free after loop
        const int type = bx / 6;           // 0=Q, 1=K, 2=V
#pragma unroll
        for (int i = 0; i < MF; ++i)
#pragma unroll
            for (int j = 0; j < 4; ++j)
#pragma unroll
                for (int r = 0; r < 4; ++r) {
                    const int rowl = wm + i * 16 + (lane >> 4) * 4 + r;
                    const int coll = wn + (lane & 15) + j * 16;
                    const short sv16 = f2b(acc[i][j][r] + bias[n0 + coll]);
                    if (type == 2) T[coll * 130 + rowl] = sv16;   // V stored transposed
                    else           T[rowl * 130 + coll] = sv16;
                }
        __syncthreads();
        if (type == 0) {
#pragma unroll
            for (int p = 0; p < 8; ++p) {
                int flat = p * 2048 + t * 8;
                int row = flat >> 7, c = flat & 127;
                *(short8*)&((short*)Cout)[(size_t)(m0 + row) * 768 + n0 + c] =
                    *(const short8*)&T[row * 130 + c];
            }
        } else if (type == 1) {
            const int hbase = (n0 - 768) >> 6;
#pragma unroll
            for (int p = 0; p < 8; ++p) {
                int q = p * 256 + t;
                int l = q >> 4, hh = (q >> 3) & 1, cc = q & 7;
                int g = m0 + l, b = g / 576, lg = g - b * 576;
                int scc = cc ^ (l & 7);
                *(short8*)&aux_kp[(((size_t)b * 12 + hbase + hh) * 576 + lg) * 64 + cc * 8] =
                    *(const short8*)&T[l * 130 + hh * 64 + scc * 8];
            }
        } else {
            const int hbase = (n0 - 1536) >> 6;
#pragma unroll
            for (int p = 0; p < 8; ++p) {
                int q = p * 256 + t;
                int coll = q >> 4, lc = (q >> 3) & 1, cc = q & 7;
                int hh = coll >> 6, dd = coll & 63;
                int gb = m0 + lc * 64, b = gb / 576, lgb = gb - b * 576;
                int scc = cc ^ (dd & 7);
                *(short8*)&aux_vt[(((size_t)b * 12 + hbase + hh) * 64 + dd) * 576 + lgb + cc * 8] =
                    *(const short8*)&T[coll * 130 + lc * 64 + scc * 8];
            }
        }
        return;
    }

    const int colb = n0 + wn + (lane & 15);
    const int rowb = m0 + wm + ((lane >> 4) * 4);
#pragma unroll
    for (int i = 0; i < MF; ++i) {
#pragma unroll
        for (int j = 0; j < 4; ++j) {
            const int col = colb + j * 16;
            const float bv = bias[col];
#pragma unroll
            for (int r = 0; r < 4; ++r) {
                const int row = rowb + i * 16 + r;
                float v = acc[i][j][r] + bv;
                if constexpr (ADD_POS) v += pos[(size_t)(row % LSEQ) * N + col];
                if constexpr (RES == 1) v += ((const float*)res)[(size_t)row * N + col];
                if constexpr (RES == 2) v += b2f(((const short*)res)[(size_t)row * N + col]);
                if constexpr (LEAKY)   v = v >= 0.f ? v : 0.01f * v;
                if constexpr (OUTM == 1) {
                    ((float*)Cout)[(size_t)row * N + col] = v;
                } else if constexpr (OUTM == 2) {
                    ((float*)Cout)[(size_t)row * N + col] = v;
                    aux_kp[(size_t)row * N + col] = f2b(v);
                } else {
                    ((short*)Cout)[(size_t)row * N + col] = f2b(v);
                }
            }
        }
    }
}

// ---------------- split-K x2 GEMM, 128x128 tile, BK=64, DEPTH=2 (64 KB LDS, 2 blocks/CU) ------
__global__ __launch_bounds__(256)
void gemm_sk2(const short* __restrict__ A, const short* __restrict__ Bt,
              float* __restrict__ P0, float* __restrict__ P1, int N, int K)
{
    __shared__ short As[2 * 128 * 64];
    __shared__ short Bs[2 * 128 * 64];
    int bx = blockIdx.x, by = blockIdx.y;
    xcd_remap(bx, by);
    const int t    = threadIdx.x;
    const int lane = t & 63;
    const int w    = t >> 6;
    const int m0   = by * 128;
    const int n0   = bx * 128;
    const int wm   = (w >> 1) * 64;
    const int wn   = (w & 1) * 64;
    const int klen  = K >> 1;
    const int kbase = blockIdx.z * klen;

    floatx4 acc[4][4];
#pragma unroll
    for (int i = 0; i < 4; ++i)
#pragma unroll
        for (int j = 0; j < 4; ++j)
            acc[i][j] = (floatx4){0.f, 0.f, 0.f, 0.f};

    const int srow = t >> 3;
    const int sch  = t & 7;
    const short* Ag = A  + (size_t)m0 * K + kbase;
    const short* Bg = Bt + (size_t)n0 * K + kbase;

#define STAGE(buf, k0)                                                              \
    {                                                                               \
        _Pragma("unroll")                                                           \
        for (int i = 0; i < 4; ++i) {                                               \
            int row = srow + i * 32;                                                \
            GLDS16(Ag + (size_t)row * K + (k0) + ((sch ^ (row & 7)) << 3),          \
                   &As[(buf) * 8192 + (size_t)(t + i * 256) * 8]);                  \
        }                                                                           \
        _Pragma("unroll")                                                           \
        for (int i = 0; i < 4; ++i) {                                               \
            int row = srow + i * 32;                                                \
            GLDS16(Bg + (size_t)row * K + (k0) + ((sch ^ (row & 7)) << 3),          \
                   &Bs[(buf) * 8192 + (size_t)(t + i * 256) * 8]);                  \
        }                                                                           \
    }

    STAGE(0, 0);
    __syncthreads();
    int cur = 0;
    for (int k0 = 0; k0 < klen; k0 += 64) {
        if (k0 + 64 < klen) STAGE(cur ^ 1, k0 + 64);
#pragma unroll
        for (int ks = 0; ks < 2; ++ks) {
            short8 af[4], bf[4];
#pragma unroll
            for (int i = 0; i < 4; ++i) {
                int row = wm + i * 16 + (lane & 15);
                int ch  = (ks * 4 + (lane >> 4)) ^ (row & 7);
                af[i] = *(const short8*)&As[cur * 8192 + row * 64 + ch * 8];
            }
#pragma unroll
            for (int j = 0; j < 4; ++j) {
                int row = wn + j * 16 + (lane & 15);
                int ch  = (ks * 4 + (lane >> 4)) ^ (row & 7);
                bf[j] = *(const short8*)&Bs[cur * 8192 + row * 64 + ch * 8];
            }
#pragma unroll
            for (int i = 0; i < 4; ++i)
#pragma unroll
                for (int j = 0; j < 4; ++j)
                    acc[i][j] = __builtin_amdgcn_mfma_f32_16x16x32_bf16(af[i], bf[j], acc[i][j], 0, 0, 0);
        }
        __syncthreads();
        cur ^= 1;
    }
#undef STAGE

    float* P = blockIdx.z ? P1 : P0;
    const int colb = n0 + wn + (lane & 15);
    const int rowb = m0 + wm + ((lane >> 4) * 4);
#pragma unroll
    for (int i = 0; i < 4; ++i)
#pragma unroll
        for (int j = 0; j < 4; ++j)
#pragma unroll
            for (int r = 0; r < 4; ++r)
                P[(size_t)(rowb + i * 16 + r) * N + colb + j * 16] = acc[i][j][r];
}

// ---------------- split-K combine + epilogue + FUSED LayerNorm (row-per-wave) ----------------
template<int RES, bool ADD_POS, int LNMODE>
__global__ __launch_bounds__(256)
void combineln(const float* __restrict__ P0, const float* __restrict__ P1,
               const float* __restrict__ bias, const float* __restrict__ pos,
               const void* __restrict__ res,
               const float* __restrict__ g, const float* __restrict__ lb,
               float* __restrict__ hout, short* __restrict__ bout)
{
    const int w = threadIdx.x >> 6, lane = threadIdx.x & 63;
    const int row = blockIdx.x * 4 + w;
    const size_t base = (size_t)row * 768;
    float v[3][4];
    float s = 0.f, ss = 0.f;
#pragma unroll
    for (int q = 0; q < 3; ++q) {
        const int col = q * 256 + lane * 4;
        floatx4 a  = *(const floatx4*)&P0[base + col];
        floatx4 b  = *(const floatx4*)&P1[base + col];
        floatx4 bv = *(const floatx4*)&bias[col];
        floatx4 t;
#pragma unroll
        for (int j = 0; j < 4; ++j) t[j] = a[j] + b[j] + bv[j];
        if constexpr (ADD_POS) {
            floatx4 p = *(const floatx4*)&pos[(size_t)(row % LSEQ) * 768 + col];
#pragma unroll
            for (int j = 0; j < 4; ++j) t[j] += p[j];
        }
        if constexpr (RES == 1) {
            floatx4 rr = *(const floatx4*)&((const float*)res)[base + col];
#pragma unroll
            for (int j = 0; j < 4; ++j) t[j] += rr[j];
        }
        if constexpr (RES == 2) {
            short4v rr = *(const short4v*)&((const short*)res)[base + col];
#pragma unroll
            for (int j = 0; j < 4; ++j) t[j] += b2f(rr[j]);
        }
#pragma unroll
        for (int j = 0; j < 4; ++j) { v[q][j] = t[j]; s += t[j]; ss += t[j] * t[j]; }
        *(floatx4*)&hout[base + col] = t;
    }
#pragma unroll
    for (int m = 1; m < 64; m <<= 1) {
        s  += __shfl_xor(s, m, 64);
        ss += __shfl_xor(ss, m, 64);
    }
    const float mean = s * (1.f / 768.f);
    const float var  = ss * (1.f / 768.f) - mean * mean;
    const float rstd = rsqrtf(var + 1e-5f);
#pragma unroll
    for (int q = 0; q < 3; ++q) {
        const int col = q * 256 + lane * 4;
        short4v ob;
        if constexpr (LNMODE == 1) {
            floatx4 gv = *(const floatx4*)&g[col];
            floatx4 bv = *(const floatx4*)&lb[col];
#pragma unroll
            for (int j = 0; j < 4; ++j) ob[j] = f2b((v[q][j] - mean) * rstd * gv[j] + bv[j]);
        } else {
#pragma unroll
            for (int j = 0; j < 4; ++j) ob[j] = f2b(v[q][j]);
        }
        *(short4v*)&bout[base + col] = ob;
    }
}

// ---------------- element-wise split-K combine (proj; no LN) ----------------
template<int RES, bool ADD_POS, int OUTM>
__global__ __launch_bounds__(256)
void combinek(const float* __restrict__ P0, const float* __restrict__ P1,
              const float* __restrict__ bias, const float* __restrict__ pos,
              const void* __restrict__ res, float* __restrict__ out,
              short* __restrict__ auxb)
{
    const size_t i4 = ((size_t)blockIdx.x * 256 + threadIdx.x) * 4;
    const int row = (int)(i4 / 768);
    const int col = (int)(i4 % 768);
    floatx4 a = *(const floatx4*)&P0[i4];
    floatx4 b = *(const floatx4*)&P1[i4];
    floatx4 bv = *(const floatx4*)&bias[col];
    floatx4 v;
#pragma unroll
    for (int j = 0; j < 4; ++j) v[j] = a[j] + b[j] + bv[j];
    if constexpr (ADD_POS) {
        floatx4 p = *(const floatx4*)&pos[(size_t)(row % LSEQ) * 768 + col];
#pragma unroll
        for (int j = 0; j < 4; ++j) v[j] += p[j];
    }
    if constexpr (RES == 1) {
        floatx4 rr = *(const floatx4*)&((const float*)res)[i4];
#pragma unroll
        for (int j = 0; j < 4; ++j) v[j] += rr[j];
    }
    if constexpr (RES == 2) {
        short4v rr = *(const short4v*)&((const short*)res)[i4];
#pragma unroll
        for (int j = 0; j < 4; ++j) v[j] += b2f(rr[j]);
    }
    *(floatx4*)&out[i4] = v;
    if constexpr (OUTM == 2) {
        short4v ob;
#pragma unroll
        for (int j = 0; j < 4; ++j) ob[j] = f2b(v[j]);
        *(short4v*)&auxb[i4] = ob;
    }
}

// ---------------- MFMA flash attention. grid (9 qtiles, 96 bh), block 256 = 4 waves ----------------
__global__ __launch_bounds__(256)
void attn_mfma(const short* __restrict__ qbuf, const short* __restrict__ kp,
               const short* __restrict__ vt, short* __restrict__ oout, int causal)
{
    const int qt = blockIdx.x, bh = blockIdx.y;
    const int b = bh / 12, h = bh % 12;
    const int t = threadIdx.x, lane = t & 63, w = t >> 6;

    __shared__ short Ks[64 * 64];
    __shared__ short Vs[64 * 64];
    __shared__ short Plds[4][16][72];

    const int nrow = lane & 15;
    const int kch  = (lane >> 4) * 8;
    const int swz  = (lane & 7) << 3;

    short8 aq[2];
    {
        const short* qrow = qbuf + ((size_t)(b * LSEQ) + qt * 64 + w * 16 + nrow) * 768 + h * 64 + kch;
        aq[0] = *(const short8*)qrow;
        aq[1] = *(const short8*)(qrow + 32);
    }

    float m[4], lsum[4];
    floatx4 oacc[4];
#pragma unroll
    for (int r = 0; r < 4; ++r) { m[r] = -3e38f; lsum[r] = 0.f; }
#pragma unroll
    for (int j = 0; j < 4; ++j) oacc[j] = (floatx4){0.f, 0.f, 0.f, 0.f};

    const int ktend = causal ? qt : 8;
    const short* ksrc = kp + ((size_t)bh * LSEQ) * 64;
    const short* vsrc = vt + ((size_t)bh * 64) * LSEQ;

    for (int kt = 0; kt <= ktend; ++kt) {
        __syncthreads();
        {
            const short* kt_src = ksrc + (size_t)(kt * 64) * 64;
            GLDS16(kt_src + (size_t)t * 8,          &Ks[(size_t)t * 8]);
            GLDS16(kt_src + (size_t)(t + 256) * 8,  &Ks[(size_t)(t + 256) * 8]);
            int f0 = t, f1 = t + 256;
            GLDS16(vsrc + (size_t)(f0 >> 3) * LSEQ + kt * 64 + (f0 & 7) * 8, &Vs[(size_t)f0 * 8]);
            GLDS16(vsrc + (size_t)(f1 >> 3) * LSEQ + kt * 64 + (f1 & 7) * 8, &Vs[(size_t)f1 * 8]);
        }
        __syncthreads();

        floatx4 sc[4];
#pragma unroll
        for (int j = 0; j < 4; ++j) sc[j] = (floatx4){0.f, 0.f, 0.f, 0.f};
#pragma unroll
        for (int s = 0; s < 2; ++s) {
#pragma unroll
            for (int j = 0; j < 4; ++j) {
                short8 bk = *(const short8*)&Ks[(16 * j + nrow) * 64 + ((kch + 32 * s) ^ swz)];
                sc[j] = __builtin_amdgcn_mfma_f32_16x16x32_bf16(aq[s], bk, sc[j], 0, 0, 0);
            }
        }
        float sv[4][4];
#pragma unroll
        for (int j = 0; j < 4; ++j)
#pragma unroll
            for (int r = 0; r < 4; ++r) {
                float v = sc[j][r] * 0.125f;
                if (causal && kt == qt) {
                    int key = kt * 64 + 16 * j + nrow;
                    int qr  = qt * 64 + w * 16 + (lane >> 4) * 4 + r;
                    if (key > qr) v = -1e12f;
                }
                sv[j][r] = v;
            }
#pragma unroll
        for (int r = 0; r < 4; ++r) {
            float tm = fmaxf(fmaxf(sv[0][r], sv[1][r]), fmaxf(sv[2][r], sv[3][r]));
            tm = fmaxf(tm, __shfl_xor(tm, 1, 64));
            tm = fmaxf(tm, __shfl_xor(tm, 2, 64));
            tm = fmaxf(tm, __shfl_xor(tm, 4, 64));
            tm = fmaxf(tm, __shfl_xor(tm, 8, 64));
            float nm = fmaxf(m[r], tm);
            float c  = __expf(m[r] - nm);
            m[r] = nm;
            float ps = 0.f;
#pragma unroll
            for (int j = 0; j < 4; ++j) {
                float p = __expf(sv[j][r] - nm);
                sv[j][r] = p;
                ps += p;
            }
            lsum[r] = lsum[r] * c + ps;
#pragma unroll
            for (int j = 0; j < 4; ++j) oacc[j][r] *= c;
        }
#pragma unroll
        for (int j = 0; j < 4; ++j)
#pragma unroll
            for (int r = 0; r < 4; ++r)
                Plds[w][(lane >> 4) * 4 + r][16 * j + nrow] = f2b(sv[j][r]);
        short8 ap[2];
#pragma unroll
        for (int s = 0; s < 2; ++s)
            ap[s] = *(const short8*)&Plds[w][nrow][kch + 32 * s];
#pragma unroll
        for (int s = 0; s < 2; ++s) {
#pragma unroll
            for (int j = 0; j < 4; ++j) {
                short8 bv = *(const short8*)&Vs[(16 * j + nrow) * 64 + ((kch + 32 * s) ^ swz)];
                oacc[j] = __builtin_amdgcn_mfma_f32_16x16x32_bf16(ap[s], bv, oacc[j], 0, 0, 0);
            }
        }
    }

    float inv[4];
#pragma unroll
    for (int r = 0; r < 4; ++r) {
        float L = lsum[r];
        L += __shfl_xor(L, 1, 64);
        L += __shfl_xor(L, 2, 64);
        L += __shfl_xor(L, 4, 64);
        L += __shfl_xor(L, 8, 64);
        inv[r] = 1.f / L;
    }
#pragma unroll
    for (int j = 0; j < 4; ++j)
#pragma unroll
        for (int r = 0; r < 4; ++r) {
            size_t lq = (size_t)qt * 64 + w * 16 + (lane >> 4) * 4 + r;
            oout[((size_t)bh * LSEQ + lq) * 64 + 16 * j + nrow] = f2b(oacc[j][r] * inv[r]);
        }
}

// ---------------- transposes ----------------
__global__ void transpose_f2b(const float* __restrict__ in, short* __restrict__ out,
                              int R, int C, long long ibs, long long obs)
{
    __shared__ float tile[32][33];
    const int b = blockIdx.z;
    const float* inb = in + (long long)b * ibs;
    short* outb = out + (long long)b * obs;
    const int r0 = blockIdx.y * 32, c0 = blockIdx.x * 32;
    const int tx = threadIdx.x, ty = threadIdx.y;
#pragma unroll
    for (int i = 0; i < 32; i += 8) tile[ty + i][tx] = inb[(size_t)(r0 + ty + i) * C + c0 + tx];
    __syncthreads();
#pragma unroll
    for (int i = 0; i < 32; i += 8) outb[(size_t)(c0 + ty + i) * R + r0 + tx] = f2b(tile[tx][ty + i]);
}

__global__ void transpose_f2f(const float* __restrict__ in, float* __restrict__ out,
                              int R, int C, long long ibs, long long obs)
{
    __shared__ float tile[32][33];
    const int b = blockIdx.z;
    const float* inb = in + (long long)b * ibs;
    float* outb = out + (long long)b * obs;
    const int r0 = blockIdx.y * 32, c0 = blockIdx.x * 32;
    const int tx = threadIdx.x, ty = threadIdx.y;
#pragma unroll
    for (int i = 0; i < 32; i += 8) tile[ty + i][tx] = inb[(size_t)(r0 + ty + i) * C + c0 + tx];
    __syncthreads();
#pragma unroll
    for (int i = 0; i < 32; i += 8) outb[(size_t)(c0 + ty + i) * R + r0 + tx] = tile[tx][ty + i];
}

// ---------------- misc small kernels ----------------
__global__ void concat_qkv_bias(const float* __restrict__ bq, const float* __restrict__ bk,
                                const float* __restrict__ bv, float* __restrict__ out)
{
    int i = blockIdx.x * 256 + threadIdx.x;
    int layer = i / 2304, j = i % 2304;
    float v;
    if (j < 768)       v = bq[layer * 768 + j];
    else if (j < 1536) v = bk[layer * 768 + j - 768];
    else               v = bv[layer * 768 + j - 1536];
    out[i] = v;
}

__global__ void im2col_kernel(const float* __restrict__ x, short* __restrict__ xcol)
{
    const size_t idx = (size_t)blockIdx.x * 256 + threadIdx.x;
    const int k = (int)(idx % 768);
    const size_t m = idx / 768;
    const int c  = k >> 8;
    const int ky = (k >> 4) & 15;
    const int kx = k & 15;
    const int b  = (int)(m / 576);
    const int l  = (int)(m % 576);
    const int ph = l / 24, pw = l % 24;
    xcol[idx] = f2b(x[((size_t)(b * 3 + c) * 384 + ph * 16 + ky) * 384 + pw * 16 + kx]);
}

__global__ void cast_f32_b16(const float* __restrict__ in, short* __restrict__ out, int n)
{
    int i = blockIdx.x * 256 + threadIdx.x;
    if (i < n) out[i] = f2b(in[i]);
}

// ---------------- host launcher ----------------
extern "C" void kernel_launch(void* const* d_in, const int* in_sizes, int n_in,
                              void* d_out, int out_size, void* d_ws, size_t ws_size,
                              hipStream_t stream)
{
    const float* x      = (const float*)d_in[0];
    const float* conv_w = (const float*)d_in[1];
    const float* conv_b = (const float*)d_in[2];
    const float* pos    = (const float*)d_in[3];
    const float* ln0_s  = (const float*)d_in[4];
    const float* ln0_b  = (const float*)d_in[5];
    const float* Wq     = (const float*)d_in[6];
    const float* bq     = (const float*)d_in[7];
    const float* Wk     = (const float*)d_in[8];
    const float* bk     = (const float*)d_in[9];
    const float* Wv     = (const float*)d_in[10];
    const float* bv     = (const float*)d_in[11];
    const float* Wo     = (const float*)d_in[12];
    const float* bo     = (const float*)d_in[13];
    const float* ln1_s  = (const float*)d_in[14];
    const float* ln1_b  = (const float*)d_in[15];
    const float* W1     = (const float*)d_in[16];
    const float* b1     = (const float*)d_in[17];
    const float* W2     = (const float*)d_in[18];
    const float* b2     = (const float*)d_in[19];
    const float* proj_w = (const float*)d_in[20];
    const float* proj_b = (const float*)d_in[21];

    char* ws = (char*)d_ws;
    short* qkvT  = (short*)(ws);                    // [8][2304][768] bf16
    short* woT   = (short*)(ws + 28311552);         // [8][768][768]
    short* w1T   = (short*)(ws + 37748736);         // [8][3072][768]
    short* w2T   = (short*)(ws + 75497472);         // [8][768][3072]
    short* projT = (short*)(ws + 113246208);        // [768][768]
    float* qkvb  = (float*)(ws + 114425856);        // [8][2304] f32
    short* tmpA  = (short*)(ws + 114499584);        // xcol / m1 bf16; kp/vt overlay; Wo/proj partials
    float* h     = (float*)(ws + 142811136);        // residual f32 / conv-P0 / W2-P0 / final yf
    short* xn    = (short*)(ws + 156966912);        // LN0 out bf16 / hb at end
    short* xrb   = (short*)(ws + 164044800);        // LN1 out bf16
    short* qbuf  = (short*)(ws + 185278464);        // Q bf16 / f32 P1 overlay (conv, W2)
    short* o     = (short*)(ws + 206512128);        // attn out (scrambled) bf16
    short* convB = (short*)(ws + 213590016);        // conv_w cast bf16 [768][768]

    short* kp = tmpA;                               // [96][576][64] bf16 (overlay)
    short* vt = tmpA + 3538944;                     // [96][64][576] bf16
    float* tmpAF  = (float*)tmpA;                   // partial P0 (Wo, proj)
    float* tmpAF2 = tmpAF + 3538944;                // partial P1 (Wo, proj)
    float* qbufF  = (float*)qbuf;                   // partial P1 (conv, W2)

    dim3 tb(32, 8);
    transpose_f2b<<<dim3(24, 24, 8), tb, 0, stream>>>(Wq, qkvT,           768, 768, 589824, 1769472);
    transpose_f2b<<<dim3(24, 24, 8), tb, 0, stream>>>(Wk, qkvT + 589824,  768, 768, 589824, 1769472);
    transpose_f2b<<<dim3(24, 24, 8), tb, 0, stream>>>(Wv, qkvT + 1179648, 768, 768, 589824, 1769472);
    transpose_f2b<<<dim3(24, 24, 8), tb, 0, stream>>>(Wo, woT,            768, 768, 589824, 589824);
    transpose_f2b<<<dim3(96, 24, 8), tb, 0, stream>>>(W1, w1T,            768, 3072, 2359296, 2359296);
    transpose_f2b<<<dim3(24, 96, 8), tb, 0, stream>>>(W2, w2T,            3072, 768, 2359296, 2359296);
    transpose_f2b<<<dim3(24, 24, 1), tb, 0, stream>>>(proj_w, projT,      768, 768, 0, 0);
    cast_f32_b16<<<2304, 256, 0, stream>>>(conv_w, convB, 589824);
    concat_qkv_bias<<<72, 256, 0, stream>>>(bq, bk, bv, qkvb);

    // patch embed: im2col + split-K conv GEMM + combine(+pos, fused LN0[0]) -> h, xn
    im2col_kernel<<<13824, 256, 0, stream>>>(x, tmpA);
    gemm_sk2<<<dim3(6, 36, 2), 256, 0, stream>>>(tmpA, convB, h, qbufF, 768, 768);
    combineln<0, true, 1><<<1152, 256, 0, stream>>>(
        h, qbufF, conv_b, pos, nullptr, ln0_s, ln0_b, h, xn);

    for (int i = 0; i < NLAYERS; ++i) {
        // qkv GEMM (128^2 tile, LDS-coalesced split epilogue): Q->qbuf, K->kp, V->vt
        gemm_bt<4, 0, false, false, 0, true><<<dim3(18, 36), 256, 0, stream>>>(
            xn, qkvT + (size_t)i * 1769472, qkvb + i * 2304, nullptr, nullptr, qbuf, kp, vt, 2304, 768);
        attn_mfma<<<dim3(9, 96), 256, 0, stream>>>(qbuf, kp, vt, o, i == 0 ? 1 : 0);
        // Wo: split-K (P0/P1 in tmpA, kp/vt dead) + combine(+f32 h residual, fused LN1) -> h, xrb
        gemm_sk2<<<dim3(6, 36, 2), 256, 0, stream>>>(
            o, woT + (size_t)i * 589824, tmpAF, tmpAF2, 768, 768);
        combineln<1, false, 1><<<1152, 256, 0, stream>>>(
            tmpAF, tmpAF2, bo + i * 768, nullptr, h, ln1_s + i * 768, ln1_b + i * 768, h, xrb);
        // W1 (leaky, 128^2 tile) -> tmpA (clobbers Wo partials, dead)
        gemm_bt<4, 0, false, true, 0, false><<<dim3(24, 36), 256, 0, stream>>>(
            xrb, w1T + (size_t)i * 2359296, b1 + i * 3072, nullptr, nullptr, tmpA, nullptr, nullptr, 3072, 768);
        // W2: split-K (P0=h dead, P1=qbuf dead) + combine(+bf16 xrb residual, fused LN0[i+1])
        gemm_sk2<<<dim3(6, 36, 2), 256, 0, stream>>>(
            tmpA, w2T + (size_t)i * 2359296, h, qbufF, 768, 3072);
        if (i < NLAYERS - 1) {
            combineln<2, false, 1><<<1152, 256, 0, stream>>>(
                h, qbufF, b2 + i * 768, nullptr, xrb, ln0_s + (i + 1) * 768, ln0_b + (i + 1) * 768, h, xn);
        } else {
            combineln<2, false, 0><<<1152, 256, 0, stream>>>(
                h, qbufF, b2 + i * 768, nullptr, xrb, nullptr, nullptr, h, xn);
        }
    }

    // final projection (split-K into tmpA, m1 dead) + combine -> h(f32), then output scramble
    short* hb = xn;
    gemm_sk2<<<dim3(6, 36, 2), 256, 0, stream>>>(hb, projT, tmpAF, tmpAF2, 768, 768);
    combinek<0, false, 1><<<3456, 256, 0, stream>>>(
        tmpAF, tmpAF2, proj_b, nullptr, nullptr, h, nullptr);
    transpose_f2f<<<dim3(24, 18, 8), tb, 0, stream>>>(h, (float*)d_out, 576, 768, 442368, 442368);
}

// Round 22
// 1500.042 us; speedup vs baseline: 1.0593x; 1.0104x over previous
//
#include <hip/hip_runtime.h>
#include <hip/hip_bf16.h>
#include <stdint.h>

#define NLAYERS 8
#define LSEQ 576
#define EMB 768
#define NHEAD 12
#define HDIM 64
#define FFDIM 3072
#define BLROWS 4608   // B*L

typedef __attribute__((ext_vector_type(8))) short short8;
typedef __attribute__((ext_vector_type(4))) short short4v;
typedef __attribute__((ext_vector_type(4))) float floatx4;

__device__ __forceinline__ float b2f(short s) {
    union { float f; uint32_t u; } x; x.u = ((uint32_t)(uint16_t)s) << 16; return x.f;
}
__device__ __forceinline__ short f2b(float f) {
    union { float f; uint32_t u; } x; x.f = f;
    uint32_t r = x.u + 0x7fffu + ((x.u >> 16) & 1u);
    return (short)(r >> 16);
}

#define GLDS16(gp, lp) __builtin_amdgcn_global_load_lds( \
    (const __attribute__((address_space(1))) void*)(gp), \
    (__attribute__((address_space(3))) void*)(lp), 16, 0, 0)

// bijective XCD-chunked remap (m204)
__device__ __forceinline__ void xcd_remap(int& bx, int& by) {
    const int gx = gridDim.x;
    const int n  = gx * gridDim.y;
    const int orig = by * gx + bx;
    const int q = n >> 3, r = n & 7;
    const int xcd = orig & 7;
    const int wgid = (xcd < r ? xcd * (q + 1) : r * (q + 1) + (xcd - r) * q) + (orig >> 3);
    bx = wgid % gx;
    by = wgid / gx;
}

// ---------------- GEMM: C[M,N] = A[M,K](bf16) * Bt[N,K]^T (bf16) + epilogue ----------------
// BM = MF*32, BK=64, DEPTH=2 dbuf. T2 swizzle via pre-swizzled global source (rule 21).
// RES: 0 none, 1 f32, 2 bf16. OUTM: 0 bf16, 1 f32, 2 f32+bf16 copy.
// QKV (requires MF=4): LDS-staged coalesced split epilogue -> Q rows / kp chunks / vt runs.
template<int MF, int RES, bool ADD_POS, bool LEAKY, int OUTM, bool QKV>
__global__ __launch_bounds__(256)
void gemm_bt(const short* __restrict__ A, const short* __restrict__ Bt,
             const float* __restrict__ bias, const float* __restrict__ pos,
             const void* __restrict__ res, void* __restrict__ Cout,
             short* __restrict__ aux_kp, short* __restrict__ aux_vt,
             int N, int K)
{
    __shared__ short lds[2 * MF * 32 * 64 + 2 * 128 * 64];
    short* As = lds;
    short* Bs = lds + 2 * MF * 32 * 64;
    int bx = blockIdx.x, by = blockIdx.y;
    xcd_remap(bx, by);
    const int t    = threadIdx.x;
    const int lane = t & 63;
    const int w    = t >> 6;
    const int m0   = by * (MF * 32);
    const int n0   = bx * 128;
    const int wm   = (w >> 1) * (MF * 16);
    const int wn   = (w & 1) * 64;

    floatx4 acc[MF][4];
#pragma unroll
    for (int i = 0; i < MF; ++i)
#pragma unroll
        for (int j = 0; j < 4; ++j)
            acc[i][j] = (floatx4){0.f, 0.f, 0.f, 0.f};

    const int srow = t >> 3;
    const int sch  = t & 7;
    const short* Ag = A  + (size_t)m0 * K;
    const short* Bg = Bt + (size_t)n0 * K;

#define STAGE(buf, k0)                                                              \
    {                                                                               \
        _Pragma("unroll")                                                           \
        for (int i = 0; i < MF; ++i) {                                              \
            int row = srow + i * 32;                                                \
            GLDS16(Ag + (size_t)row * K + (k0) + ((sch ^ (row & 7)) << 3),          \
                   &As[(buf) * (MF * 2048) + (size_t)(t + i * 256) * 8]);           \
        }                                                                           \
        _Pragma("unroll")                                                           \
        for (int i = 0; i < 4; ++i) {                                               \
            int row = srow + i * 32;                                                \
            GLDS16(Bg + (size_t)row * K + (k0) + ((sch ^ (row & 7)) << 3),          \
                   &Bs[(buf) * 8192 + (size_t)(t + i * 256) * 8]);                  \
        }                                                                           \
    }

    STAGE(0, 0);
    __syncthreads();
    int cur = 0;
    for (int k0 = 0; k0 < K; k0 += 64) {
        if (k0 + 64 < K) STAGE(cur ^ 1, k0 + 64);
#pragma unroll
        for (int ks = 0; ks < 2; ++ks) {
            short8 af[MF], bf[4];
#pragma unroll
            for (int i = 0; i < MF; ++i) {
                int row = wm + i * 16 + (lane & 15);
                int ch  = (ks * 4 + (lane >> 4)) ^ (row & 7);
                af[i] = *(const short8*)&As[cur * (MF * 2048) + row * 64 + ch * 8];
            }
#pragma unroll
            for (int j = 0; j < 4; ++j) {
                int row = wn + j * 16 + (lane & 15);
                int ch  = (ks * 4 + (lane >> 4)) ^ (row & 7);
                bf[j] = *(const short8*)&Bs[cur * 8192 + row * 64 + ch * 8];
            }
#pragma unroll
            for (int i = 0; i < MF; ++i)
#pragma unroll
                for (int j = 0; j < 4; ++j)
                    acc[i][j] = __builtin_amdgcn_mfma_f32_16x16x32_bf16(af[i], bf[j], acc[i][j], 0, 0, 0);
        }
        __syncthreads();
        cur ^= 1;
    }
#undef STAGE

    if constexpr (QKV) {
        // ---- LDS-staged coalesced split epilogue (tile is 128x128; type per block) ----
        short* T = lds;                    // 128 x 130 bf16, LDS free after loop
        const int type = bx / 6;           // 0=Q, 1=K, 2=V
#pragma unroll
        for (int i = 0; i < MF; ++i)
#pragma unroll
            for (int j = 0; j < 4; ++j)
#pragma unroll
                for (int r = 0; r < 4; ++r) {
                    const int rowl = wm + i * 16 + (lane >> 4) * 4 + r;
                    const int coll = wn + (lane & 15) + j * 16;
                    const short sv16 = f2b(acc[i][j][r] + bias[n0 + coll]);
                    if (type == 2) T[coll * 130 + rowl] = sv16;   // V stored transposed
                    else           T[rowl * 130 + coll] = sv16;
                }
        __syncthreads();
        if (type == 0) {
#pragma unroll
            for (int p = 0; p < 8; ++p) {
                int flat = p * 2048 + t * 8;
                int row = flat >> 7, c = flat & 127;
                *(short8*)&((short*)Cout)[(size_t)(m0 + row) * 768 + n0 + c] =
                    *(const short8*)&T[row * 130 + c];
            }
        } else if (type == 1) {
            const int hbase = (n0 - 768) >> 6;
#pragma unroll
            for (int p = 0; p < 8; ++p) {
                int q = p * 256 + t;
                int l = q >> 4, hh = (q >> 3) & 1, cc = q & 7;
                int g = m0 + l, b = g / 576, lg = g - b * 576;
                int scc = cc ^ (l & 7);
                *(short8*)&aux_kp[(((size_t)b * 12 + hbase + hh) * 576 + lg) * 64 + cc * 8] =
                    *(const short8*)&T[l * 130 + hh * 64 + scc * 8];
            }
        } else {
            const int hbase = (n0 - 1536) >> 6;
#pragma unroll
            for (int p = 0; p < 8; ++p) {
                int q = p * 256 + t;
                int coll = q >> 4, lc = (q >> 3) & 1, cc = q & 7;
                int hh = coll >> 6, dd = coll & 63;
                int gb = m0 + lc * 64, b = gb / 576, lgb = gb - b * 576;
                int scc = cc ^ (dd & 7);
                *(short8*)&aux_vt[(((size_t)b * 12 + hbase + hh) * 64 + dd) * 576 + lgb + cc * 8] =
                    *(const short8*)&T[coll * 130 + lc * 64 + scc * 8];
            }
        }
        return;
    }

    const int colb = n0 + wn + (lane & 15);
    const int rowb = m0 + wm + ((lane >> 4) * 4);
#pragma unroll
    for (int i = 0; i < MF; ++i) {
#pragma unroll
        for (int j = 0; j < 4; ++j) {
            const int col = colb + j * 16;
            const float bv = bias[col];
#pragma unroll
            for (int r = 0; r < 4; ++r) {
                const int row = rowb + i * 16 + r;
                float v = acc[i][j][r] + bv;
                if constexpr (ADD_POS) v += pos[(size_t)(row % LSEQ) * N + col];
                if constexpr (RES == 1) v += ((const float*)res)[(size_t)row * N + col];
                if constexpr (RES == 2) v += b2f(((const short*)res)[(size_t)row * N + col]);
                if constexpr (LEAKY)   v = v >= 0.f ? v : 0.01f * v;
                if constexpr (OUTM == 1) {
                    ((float*)Cout)[(size_t)row * N + col] = v;
                } else if constexpr (OUTM == 2) {
                    ((float*)Cout)[(size_t)row * N + col] = v;
                    aux_kp[(size_t)row * N + col] = f2b(v);
                } else {
                    ((short*)Cout)[(size_t)row * N + col] = f2b(v);
                }
            }
        }
    }
}

// ---------------- split-K x2 GEMM, 128x128 tile, BK=64, DEPTH=2 (64 KB LDS, 2 blocks/CU) ------
__global__ __launch_bounds__(256)
void gemm_sk2(const short* __restrict__ A, const short* __restrict__ Bt,
              float* __restrict__ P0, float* __restrict__ P1, int N, int K)
{
    __shared__ short As[2 * 128 * 64];
    __shared__ short Bs[2 * 128 * 64];
    int bx = blockIdx.x, by = blockIdx.y;
    xcd_remap(bx, by);
    const int t    = threadIdx.x;
    const int lane = t & 63;
    const int w    = t >> 6;
    const int m0   = by * 128;
    const int n0   = bx * 128;
    const int wm   = (w >> 1) * 64;
    const int wn   = (w & 1) * 64;
    const int klen  = K >> 1;
    const int kbase = blockIdx.z * klen;

    floatx4 acc[4][4];
#pragma unroll
    for (int i = 0; i < 4; ++i)
#pragma unroll
        for (int j = 0; j < 4; ++j)
            acc[i][j] = (floatx4){0.f, 0.f, 0.f, 0.f};

    const int srow = t >> 3;
    const int sch  = t & 7;
    const short* Ag = A  + (size_t)m0 * K + kbase;
    const short* Bg = Bt + (size_t)n0 * K + kbase;

#define STAGE(buf, k0)                                                              \
    {                                                                               \
        _Pragma("unroll")                                                           \
        for (int i = 0; i < 4; ++i) {                                               \
            int row = srow + i * 32;                                                \
            GLDS16(Ag + (size_t)row * K + (k0) + ((sch ^ (row & 7)) << 3),          \
                   &As[(buf) * 8192 + (size_t)(t + i * 256) * 8]);                  \
        }                                                                           \
        _Pragma("unroll")                                                           \
        for (int i = 0; i < 4; ++i) {                                               \
            int row = srow + i * 32;                                                \
            GLDS16(Bg + (size_t)row * K + (k0) + ((sch ^ (row & 7)) << 3),          \
                   &Bs[(buf) * 8192 + (size_t)(t + i * 256) * 8]);                  \
        }                                                                           \
    }

    STAGE(0, 0);
    __syncthreads();
    int cur = 0;
    for (int k0 = 0; k0 < klen; k0 += 64) {
        if (k0 + 64 < klen) STAGE(cur ^ 1, k0 + 64);
#pragma unroll
        for (int ks = 0; ks < 2; ++ks) {
            short8 af[4], bf[4];
#pragma unroll
            for (int i = 0; i < 4; ++i) {
                int row = wm + i * 16 + (lane & 15);
                int ch  = (ks * 4 + (lane >> 4)) ^ (row & 7);
                af[i] = *(const short8*)&As[cur * 8192 + row * 64 + ch * 8];
            }
#pragma unroll
            for (int j = 0; j < 4; ++j) {
                int row = wn + j * 16 + (lane & 15);
                int ch  = (ks * 4 + (lane >> 4)) ^ (row & 7);
                bf[j] = *(const short8*)&Bs[cur * 8192 + row * 64 + ch * 8];
            }
#pragma unroll
            for (int i = 0; i < 4; ++i)
#pragma unroll
                for (int j = 0; j < 4; ++j)
                    acc[i][j] = __builtin_amdgcn_mfma_f32_16x16x32_bf16(af[i], bf[j], acc[i][j], 0, 0, 0);
        }
        __syncthreads();
        cur ^= 1;
    }
#undef STAGE

    float* P = blockIdx.z ? P1 : P0;
    const int colb = n0 + wn + (lane & 15);
    const int rowb = m0 + wm + ((lane >> 4) * 4);
#pragma unroll
    for (int i = 0; i < 4; ++i)
#pragma unroll
        for (int j = 0; j < 4; ++j)
#pragma unroll
            for (int r = 0; r < 4; ++r)
                P[(size_t)(rowb + i * 16 + r) * N + colb + j * 16] = acc[i][j][r];
}

// ---------------- split-K combine + epilogue + FUSED LayerNorm (row-per-wave) ----------------
template<int RES, bool ADD_POS, int LNMODE>
__global__ __launch_bounds__(256)
void combineln(const float* __restrict__ P0, const float* __restrict__ P1,
               const float* __restrict__ bias, const float* __restrict__ pos,
               const void* __restrict__ res,
               const float* __restrict__ g, const float* __restrict__ lb,
               float* __restrict__ hout, short* __restrict__ bout)
{
    const int w = threadIdx.x >> 6, lane = threadIdx.x & 63;
    const int row = blockIdx.x * 4 + w;
    const size_t base = (size_t)row * 768;
    float v[3][4];
    float s = 0.f, ss = 0.f;
#pragma unroll
    for (int q = 0; q < 3; ++q) {
        const int col = q * 256 + lane * 4;
        floatx4 a  = *(const floatx4*)&P0[base + col];
        floatx4 b  = *(const floatx4*)&P1[base + col];
        floatx4 bv = *(const floatx4*)&bias[col];
        floatx4 t;
#pragma unroll
        for (int j = 0; j < 4; ++j) t[j] = a[j] + b[j] + bv[j];
        if constexpr (ADD_POS) {
            floatx4 p = *(const floatx4*)&pos[(size_t)(row % LSEQ) * 768 + col];
#pragma unroll
            for (int j = 0; j < 4; ++j) t[j] += p[j];
        }
        if constexpr (RES == 1) {
            floatx4 rr = *(const floatx4*)&((const float*)res)[base + col];
#pragma unroll
            for (int j = 0; j < 4; ++j) t[j] += rr[j];
        }
        if constexpr (RES == 2) {
            short4v rr = *(const short4v*)&((const short*)res)[base + col];
#pragma unroll
            for (int j = 0; j < 4; ++j) t[j] += b2f(rr[j]);
        }
#pragma unroll
        for (int j = 0; j < 4; ++j) { v[q][j] = t[j]; s += t[j]; ss += t[j] * t[j]; }
        *(floatx4*)&hout[base + col] = t;
    }
#pragma unroll
    for (int m = 1; m < 64; m <<= 1) {
        s  += __shfl_xor(s, m, 64);
        ss += __shfl_xor(ss, m, 64);
    }
    const float mean = s * (1.f / 768.f);
    const float var  = ss * (1.f / 768.f) - mean * mean;
    const float rstd = rsqrtf(var + 1e-5f);
#pragma unroll
    for (int q = 0; q < 3; ++q) {
        const int col = q * 256 + lane * 4;
        short4v ob;
        if constexpr (LNMODE == 1) {
            floatx4 gv = *(const floatx4*)&g[col];
            floatx4 bv = *(const floatx4*)&lb[col];
#pragma unroll
            for (int j = 0; j < 4; ++j) ob[j] = f2b((v[q][j] - mean) * rstd * gv[j] + bv[j]);
        } else {
#pragma unroll
            for (int j = 0; j < 4; ++j) ob[j] = f2b(v[q][j]);
        }
        *(short4v*)&bout[base + col] = ob;
    }
}

// ---------------- element-wise split-K combine (proj; no LN) ----------------
template<int RES, bool ADD_POS, int OUTM>
__global__ __launch_bounds__(256)
void combinek(const float* __restrict__ P0, const float* __restrict__ P1,
              const float* __restrict__ bias, const float* __restrict__ pos,
              const void* __restrict__ res, float* __restrict__ out,
              short* __restrict__ auxb)
{
    const size_t i4 = ((size_t)blockIdx.x * 256 + threadIdx.x) * 4;
    const int row = (int)(i4 / 768);
    const int col = (int)(i4 % 768);
    floatx4 a = *(const floatx4*)&P0[i4];
    floatx4 b = *(const floatx4*)&P1[i4];
    floatx4 bv = *(const floatx4*)&bias[col];
    floatx4 v;
#pragma unroll
    for (int j = 0; j < 4; ++j) v[j] = a[j] + b[j] + bv[j];
    if constexpr (ADD_POS) {
        floatx4 p = *(const floatx4*)&pos[(size_t)(row % LSEQ) * 768 + col];
#pragma unroll
        for (int j = 0; j < 4; ++j) v[j] += p[j];
    }
    if constexpr (RES == 1) {
        floatx4 rr = *(const floatx4*)&((const float*)res)[i4];
#pragma unroll
        for (int j = 0; j < 4; ++j) v[j] += rr[j];
    }
    if constexpr (RES == 2) {
        short4v rr = *(const short4v*)&((const short*)res)[i4];
#pragma unroll
        for (int j = 0; j < 4; ++j) v[j] += b2f(rr[j]);
    }
    *(floatx4*)&out[i4] = v;
    if constexpr (OUTM == 2) {
        short4v ob;
#pragma unroll
        for (int j = 0; j < 4; ++j) ob[j] = f2b(v[j]);
        *(short4v*)&auxb[i4] = ob;
    }
}

// ---------------- MFMA flash attention, static double-tile. grid (9, 96), 4 waves -------------
// Pairs of 64-key tiles share one softmax pass + one barrier pair (all array indices static;
// R20's runtime-indexed-scratch failure mode avoided). Odd tail tile uses the single-tile body.
// LDS ~49 KB -> 3 blocks/CU.
__global__ __launch_bounds__(256)
void attn_mfma(const short* __restrict__ qbuf, const short* __restrict__ kp,
               const short* __restrict__ vt, short* __restrict__ oout, int causal)
{
    const int qt = blockIdx.x, bh = blockIdx.y;
    const int b = bh / 12, h = bh % 12;
    const int t = threadIdx.x, lane = t & 63, w = t >> 6;

    __shared__ short Ks[2][64 * 64];
    __shared__ short Vs[2][64 * 64];
    __shared__ short Plds[4][16][136];

    const int nrow = lane & 15;
    const int kch  = (lane >> 4) * 8;
    const int swz  = (lane & 7) << 3;

    short8 aq[2];
    {
        const short* qrow = qbuf + ((size_t)(b * LSEQ) + qt * 64 + w * 16 + nrow) * 768 + h * 64 + kch;
        aq[0] = *(const short8*)qrow;
        aq[1] = *(const short8*)(qrow + 32);
    }

    float m[4], lsum[4];
    floatx4 oacc[4];
#pragma unroll
    for (int r = 0; r < 4; ++r) { m[r] = -3e38f; lsum[r] = 0.f; }
#pragma unroll
    for (int j = 0; j < 4; ++j) oacc[j] = (floatx4){0.f, 0.f, 0.f, 0.f};

    const int ktend = causal ? qt : 8;
    const short* ksrc = kp + ((size_t)bh * LSEQ) * 64;
    const short* vsrc = vt + ((size_t)bh * 64) * LSEQ;

#define STAGE_KV(buf, kt)                                                             \
    {                                                                                 \
        const short* kt_src = ksrc + (size_t)((kt) * 64) * 64;                        \
        GLDS16(kt_src + (size_t)t * 8,         &Ks[buf][(size_t)t * 8]);              \
        GLDS16(kt_src + (size_t)(t + 256) * 8, &Ks[buf][(size_t)(t + 256) * 8]);      \
        GLDS16(vsrc + (size_t)(t >> 3) * LSEQ + (kt) * 64 + (t & 7) * 8,              \
               &Vs[buf][(size_t)t * 8]);                                              \
        GLDS16(vsrc + (size_t)((t + 256) >> 3) * LSEQ + (kt) * 64 + (t & 7) * 8,      \
               &Vs[buf][(size_t)(t + 256) * 8]);                                      \
    }

    int kt = 0;
    for (; kt + 1 <= ktend; kt += 2) {
        __syncthreads();
        STAGE_KV(0, kt);
        STAGE_KV(1, kt + 1);
        __syncthreads();

        floatx4 sc0[4], sc1[4];
#pragma unroll
        for (int j = 0; j < 4; ++j) {
            sc0[j] = (floatx4){0.f, 0.f, 0.f, 0.f};
            sc1[j] = (floatx4){0.f, 0.f, 0.f, 0.f};
        }
#pragma unroll
        for (int s = 0; s < 2; ++s)
#pragma unroll
            for (int j = 0; j < 4; ++j) {
                short8 bk0 = *(const short8*)&Ks[0][(16 * j + nrow) * 64 + ((kch + 32 * s) ^ swz)];
                sc0[j] = __builtin_amdgcn_mfma_f32_16x16x32_bf16(aq[s], bk0, sc0[j], 0, 0, 0);
                short8 bk1 = *(const short8*)&Ks[1][(16 * j + nrow) * 64 + ((kch + 32 * s) ^ swz)];
                sc1[j] = __builtin_amdgcn_mfma_f32_16x16x32_bf16(aq[s], bk1, sc1[j], 0, 0, 0);
            }

        float sv0[4][4], sv1[4][4];
#pragma unroll
        for (int j = 0; j < 4; ++j)
#pragma unroll
            for (int r = 0; r < 4; ++r) {
                float v0 = sc0[j][r] * 0.125f;
                float v1 = sc1[j][r] * 0.125f;
                if (causal) {
                    const int qr = qt * 64 + w * 16 + (lane >> 4) * 4 + r;
                    if (kt == qt     && kt * 64 + 16 * j + nrow > qr)       v0 = -1e12f;
                    if (kt + 1 == qt && (kt + 1) * 64 + 16 * j + nrow > qr) v1 = -1e12f;
                }
                sv0[j][r] = v0;
                sv1[j][r] = v1;
            }
#pragma unroll
        for (int r = 0; r < 4; ++r) {
            float tm = fmaxf(fmaxf(sv0[0][r], sv0[1][r]), fmaxf(sv0[2][r], sv0[3][r]));
            tm = fmaxf(tm, fmaxf(fmaxf(sv1[0][r], sv1[1][r]), fmaxf(sv1[2][r], sv1[3][r])));
            tm = fmaxf(tm, __shfl_xor(tm, 1, 64));
            tm = fmaxf(tm, __shfl_xor(tm, 2, 64));
            tm = fmaxf(tm, __shfl_xor(tm, 4, 64));
            tm = fmaxf(tm, __shfl_xor(tm, 8, 64));
            float nm = fmaxf(m[r], tm);
            float c  = __expf(m[r] - nm);
            m[r] = nm;
            float ps = 0.f;
#pragma unroll
            for (int j = 0; j < 4; ++j) {
                float p0 = __expf(sv0[j][r] - nm);
                sv0[j][r] = p0;
                ps += p0;
                float p1 = __expf(sv1[j][r] - nm);
                sv1[j][r] = p1;
                ps += p1;
            }
            lsum[r] = lsum[r] * c + ps;
#pragma unroll
            for (int j = 0; j < 4; ++j) oacc[j][r] *= c;
        }
#pragma unroll
        for (int j = 0; j < 4; ++j)
#pragma unroll
            for (int r = 0; r < 4; ++r) {
                Plds[w][(lane >> 4) * 4 + r][16 * j + nrow]      = f2b(sv0[j][r]);
                Plds[w][(lane >> 4) * 4 + r][64 + 16 * j + nrow] = f2b(sv1[j][r]);
            }
        short8 ap0[2], ap1[2];
#pragma unroll
        for (int s = 0; s < 2; ++s) {
            ap0[s] = *(const short8*)&Plds[w][nrow][kch + 32 * s];
            ap1[s] = *(const short8*)&Plds[w][nrow][64 + kch + 32 * s];
        }
#pragma unroll
        for (int s = 0; s < 2; ++s)
#pragma unroll
            for (int j = 0; j < 4; ++j) {
                short8 bv0 = *(const short8*)&Vs[0][(16 * j + nrow) * 64 + ((kch + 32 * s) ^ swz)];
                oacc[j] = __builtin_amdgcn_mfma_f32_16x16x32_bf16(ap0[s], bv0, oacc[j], 0, 0, 0);
                short8 bv1 = *(const short8*)&Vs[1][(16 * j + nrow) * 64 + ((kch + 32 * s) ^ swz)];
                oacc[j] = __builtin_amdgcn_mfma_f32_16x16x32_bf16(ap1[s], bv1, oacc[j], 0, 0, 0);
            }
    }

    if (kt <= ktend) {
        // single-tile tail (R17-identical body, buffer 0)
        __syncthreads();
        STAGE_KV(0, kt);
        __syncthreads();

        floatx4 sc[4];
#pragma unroll
        for (int j = 0; j < 4; ++j) sc[j] = (floatx4){0.f, 0.f, 0.f, 0.f};
#pragma unroll
        for (int s = 0; s < 2; ++s) {
#pragma unroll
            for (int j = 0; j < 4; ++j) {
                short8 bk = *(const short8*)&Ks[0][(16 * j + nrow) * 64 + ((kch + 32 * s) ^ swz)];
                sc[j] = __builtin_amdgcn_mfma_f32_16x16x32_bf16(aq[s], bk, sc[j], 0, 0, 0);
            }
        }
        float sv[4][4];
#pragma unroll
        for (int j = 0; j < 4; ++j)
#pragma unroll
            for (int r = 0; r < 4; ++r) {
                float v = sc[j][r] * 0.125f;
                if (causal && kt == qt) {
                    int key = kt * 64 + 16 * j + nrow;
                    int qr  = qt * 64 + w * 16 + (lane >> 4) * 4 + r;
                    if (key > qr) v = -1e12f;
                }
                sv[j][r] = v;
            }
#pragma unroll
        for (int r = 0; r < 4; ++r) {
            float tm = fmaxf(fmaxf(sv[0][r], sv[1][r]), fmaxf(sv[2][r], sv[3][r]));
            tm = fmaxf(tm, __shfl_xor(tm, 1, 64));
            tm = fmaxf(tm, __shfl_xor(tm, 2, 64));
            tm = fmaxf(tm, __shfl_xor(tm, 4, 64));
            tm = fmaxf(tm, __shfl_xor(tm, 8, 64));
            float nm = fmaxf(m[r], tm);
            float c  = __expf(m[r] - nm);
            m[r] = nm;
            float ps = 0.f;
#pragma unroll
            for (int j = 0; j < 4; ++j) {
                float p = __expf(sv[j][r] - nm);
                sv[j][r] = p;
                ps += p;
            }
            lsum[r] = lsum[r] * c + ps;
#pragma unroll
            for (int j = 0; j < 4; ++j) oacc[j][r] *= c;
        }
#pragma unroll
        for (int j = 0; j < 4; ++j)
#pragma unroll
            for (int r = 0; r < 4; ++r)
                Plds[w][(lane >> 4) * 4 + r][16 * j + nrow] = f2b(sv[j][r]);
        short8 ap[2];
#pragma unroll
        for (int s = 0; s < 2; ++s)
            ap[s] = *(const short8*)&Plds[w][nrow][kch + 32 * s];
#pragma unroll
        for (int s = 0; s < 2; ++s) {
#pragma unroll
            for (int j = 0; j < 4; ++j) {
                short8 bv = *(const short8*)&Vs[0][(16 * j + nrow) * 64 + ((kch + 32 * s) ^ swz)];
                oacc[j] = __builtin_amdgcn_mfma_f32_16x16x32_bf16(ap[s], bv, oacc[j], 0, 0, 0);
            }
        }
    }
#undef STAGE_KV

    float inv[4];
#pragma unroll
    for (int r = 0; r < 4; ++r) {
        float L = lsum[r];
        L += __shfl_xor(L, 1, 64);
        L += __shfl_xor(L, 2, 64);
        L += __shfl_xor(L, 4, 64);
        L += __shfl_xor(L, 8, 64);
        inv[r] = 1.f / L;
    }
#pragma unroll
    for (int j = 0; j < 4; ++j)
#pragma unroll
        for (int r = 0; r < 4; ++r) {
            size_t lq = (size_t)qt * 64 + w * 16 + (lane >> 4) * 4 + r;
            oout[((size_t)bh * LSEQ + lq) * 64 + 16 * j + nrow] = f2b(oacc[j][r] * inv[r]);
        }
}

// ---------------- transposes ----------------
__global__ void transpose_f2b(const float* __restrict__ in, short* __restrict__ out,
                              int R, int C, long long ibs, long long obs)
{
    __shared__ float tile[32][33];
    const int b = blockIdx.z;
    const float* inb = in + (long long)b * ibs;
    short* outb = out + (long long)b * obs;
    const int r0 = blockIdx.y * 32, c0 = blockIdx.x * 32;
    const int tx = threadIdx.x, ty = threadIdx.y;
#pragma unroll
    for (int i = 0; i < 32; i += 8) tile[ty + i][tx] = inb[(size_t)(r0 + ty + i) * C + c0 + tx];
    __syncthreads();
#pragma unroll
    for (int i = 0; i < 32; i += 8) outb[(size_t)(c0 + ty + i) * R + r0 + tx] = f2b(tile[tx][ty + i]);
}

__global__ void transpose_f2f(const float* __restrict__ in, float* __restrict__ out,
                              int R, int C, long long ibs, long long obs)
{
    __shared__ float tile[32][33];
    const int b = blockIdx.z;
    const float* inb = in + (long long)b * ibs;
    float* outb = out + (long long)b * obs;
    const int r0 = blockIdx.y * 32, c0 = blockIdx.x * 32;
    const int tx = threadIdx.x, ty = threadIdx.y;
#pragma unroll
    for (int i = 0; i < 32; i += 8) tile[ty + i][tx] = inb[(size_t)(r0 + ty + i) * C + c0 + tx];
    __syncthreads();
#pragma unroll
    for (int i = 0; i < 32; i += 8) outb[(size_t)(c0 + ty + i) * R + r0 + tx] = tile[tx][ty + i];
}

// ---------------- misc small kernels ----------------
__global__ void concat_qkv_bias(const float* __restrict__ bq, const float* __restrict__ bk,
                                const float* __restrict__ bv, float* __restrict__ out)
{
    int i = blockIdx.x * 256 + threadIdx.x;
    int layer = i / 2304, j = i % 2304;
    float v;
    if (j < 768)       v = bq[layer * 768 + j];
    else if (j < 1536) v = bk[layer * 768 + j - 768];
    else               v = bv[layer * 768 + j - 1536];
    out[i] = v;
}

__global__ void im2col_kernel(const float* __restrict__ x, short* __restrict__ xcol)
{
    const size_t idx = (size_t)blockIdx.x * 256 + threadIdx.x;
    const int k = (int)(idx % 768);
    const size_t m = idx / 768;
    const int c  = k >> 8;
    const int ky = (k >> 4) & 15;
    const int kx = k & 15;
    const int b  = (int)(m / 576);
    const int l  = (int)(m % 576);
    const int ph = l / 24, pw = l % 24;
    xcol[idx] = f2b(x[((size_t)(b * 3 + c) * 384 + ph * 16 + ky) * 384 + pw * 16 + kx]);
}

__global__ void cast_f32_b16(const float* __restrict__ in, short* __restrict__ out, int n)
{
    int i = blockIdx.x * 256 + threadIdx.x;
    if (i < n) out[i] = f2b(in[i]);
}

// ---------------- host launcher ----------------
extern "C" void kernel_launch(void* const* d_in, const int* in_sizes, int n_in,
                              void* d_out, int out_size, void* d_ws, size_t ws_size,
                              hipStream_t stream)
{
    const float* x      = (const float*)d_in[0];
    const float* conv_w = (const float*)d_in[1];
    const float* conv_b = (const float*)d_in[2];
    const float* pos    = (const float*)d_in[3];
    const float* ln0_s  = (const float*)d_in[4];
    const float* ln0_b  = (const float*)d_in[5];
    const float* Wq     = (const float*)d_in[6];
    const float* bq     = (const float*)d_in[7];
    const float* Wk     = (const float*)d_in[8];
    const float* bk     = (const float*)d_in[9];
    const float* Wv     = (const float*)d_in[10];
    const float* bv     = (const float*)d_in[11];
    const float* Wo     = (const float*)d_in[12];
    const float* bo     = (const float*)d_in[13];
    const float* ln1_s  = (const float*)d_in[14];
    const float* ln1_b  = (const float*)d_in[15];
    const float* W1     = (const float*)d_in[16];
    const float* b1     = (const float*)d_in[17];
    const float* W2     = (const float*)d_in[18];
    const float* b2     = (const float*)d_in[19];
    const float* proj_w = (const float*)d_in[20];
    const float* proj_b = (const float*)d_in[21];

    char* ws = (char*)d_ws;
    short* qkvT  = (short*)(ws);                    // [8][2304][768] bf16
    short* woT   = (short*)(ws + 28311552);         // [8][768][768]
    short* w1T   = (short*)(ws + 37748736);         // [8][3072][768]
    short* w2T   = (short*)(ws + 75497472);         // [8][768][3072]
    short* projT = (short*)(ws + 113246208);        // [768][768]
    float* qkvb  = (float*)(ws + 114425856);        // [8][2304] f32
    short* tmpA  = (short*)(ws + 114499584);        // xcol / m1 bf16; kp/vt overlay; Wo/proj partials
    float* h     = (float*)(ws + 142811136);        // residual f32 / conv-P0 / W2-P0 / final yf
    short* xn    = (short*)(ws + 156966912);        // LN0 out bf16 / hb at end
    short* xrb   = (short*)(ws + 164044800);        // LN1 out bf16
    short* qbuf  = (short*)(ws + 185278464);        // Q bf16 / f32 P1 overlay (conv, W2)
    short* o     = (short*)(ws + 206512128);        // attn out (scrambled) bf16
    short* convB = (short*)(ws + 213590016);        // conv_w cast bf16 [768][768]

    short* kp = tmpA;                               // [96][576][64] bf16 (overlay)
    short* vt = tmpA + 3538944;                     // [96][64][576] bf16
    float* tmpAF  = (float*)tmpA;                   // partial P0 (Wo, proj)
    float* tmpAF2 = tmpAF + 3538944;                // partial P1 (Wo, proj)
    float* qbufF  = (float*)qbuf;                   // partial P1 (conv, W2)

    dim3 tb(32, 8);
    transpose_f2b<<<dim3(24, 24, 8), tb, 0, stream>>>(Wq, qkvT,           768, 768, 589824, 1769472);
    transpose_f2b<<<dim3(24, 24, 8), tb, 0, stream>>>(Wk, qkvT + 589824,  768, 768, 589824, 1769472);
    transpose_f2b<<<dim3(24, 24, 8), tb, 0, stream>>>(Wv, qkvT + 1179648, 768, 768, 589824, 1769472);
    transpose_f2b<<<dim3(24, 24, 8), tb, 0, stream>>>(Wo, woT,            768, 768, 589824, 589824);
    transpose_f2b<<<dim3(96, 24, 8), tb, 0, stream>>>(W1, w1T,            768, 3072, 2359296, 2359296);
    transpose_f2b<<<dim3(24, 96, 8), tb, 0, stream>>>(W2, w2T,            3072, 768, 2359296, 2359296);
    transpose_f2b<<<dim3(24, 24, 1), tb, 0, stream>>>(proj_w, projT,      768, 768, 0, 0);
    cast_f32_b16<<<2304, 256, 0, stream>>>(conv_w, convB, 589824);
    concat_qkv_bias<<<72, 256, 0, stream>>>(bq, bk, bv, qkvb);

    // patch embed: im2col + split-K conv GEMM + combine(+pos, fused LN0[0]) -> h, xn
    im2col_kernel<<<13824, 256, 0, stream>>>(x, tmpA);
    gemm_sk2<<<dim3(6, 36, 2), 256, 0, stream>>>(tmpA, convB, h, qbufF, 768, 768);
    combineln<0, true, 1><<<1152, 256, 0, stream>>>(
        h, qbufF, conv_b, pos, nullptr, ln0_s, ln0_b, h, xn);

    for (int i = 0; i < NLAYERS; ++i) {
        // qkv GEMM (128^2 tile, LDS-coalesced split epilogue): Q->qbuf, K->kp, V->vt
        gemm_bt<4, 0, false, false, 0, true><<<dim3(18, 36), 256, 0, stream>>>(
            xn, qkvT + (size_t)i * 1769472, qkvb + i * 2304, nullptr, nullptr, qbuf, kp, vt, 2304, 768);
        attn_mfma<<<dim3(9, 96), 256, 0, stream>>>(qbuf, kp, vt, o, i == 0 ? 1 : 0);
        // Wo: split-K (P0/P1 in tmpA, kp/vt dead) + combine(+f32 h residual, fused LN1) -> h, xrb
        gemm_sk2<<<dim3(6, 36, 2), 256, 0, stream>>>(
            o, woT + (size_t)i * 589824, tmpAF, tmpAF2, 768, 768);
        combineln<1, false, 1><<<1152, 256, 0, stream>>>(
            tmpAF, tmpAF2, bo + i * 768, nullptr, h, ln1_s + i * 768, ln1_b + i * 768, h, xrb);
        // W1 (leaky, 128^2 tile) -> tmpA (clobbers Wo partials, dead)
        gemm_bt<4, 0, false, true, 0, false><<<dim3(24, 36), 256, 0, stream>>>(
            xrb, w1T + (size_t)i * 2359296, b1 + i * 3072, nullptr, nullptr, tmpA, nullptr, nullptr, 3072, 768);
        // W2: split-K (P0=h dead, P1=qbuf dead) + combine(+bf16 xrb residual, fused LN0[i+1])
        gemm_sk2<<<dim3(6, 36, 2), 256, 0, stream>>>(
            tmpA, w2T + (size_t)i * 2359296, h, qbufF, 768, 3072);
        if (i < NLAYERS - 1) {
            combineln<2, false, 1><<<1152, 256, 0, stream>>>(
                h, qbufF, b2 + i * 768, nullptr, xrb, ln0_s + (i + 1) * 768, ln0_b + (i + 1) * 768, h, xn);
        } else {
            combineln<2, false, 0><<<1152, 256, 0, stream>>>(
                h, qbufF, b2 + i * 768, nullptr, xrb, nullptr, nullptr, h, xn);
        }
    }

    // final projection (split-K into tmpA, m1 dead) + combine -> h(f32), then output scramble
    short* hb = xn;
    gemm_sk2<<<dim3(6, 36, 2), 256, 0, stream>>>(hb, projT, tmpAF, tmpAF2, 768, 768);
    combinek<0, false, 1><<<3456, 256, 0, stream>>>(
        tmpAF, tmpAF2, proj_b, nullptr, nullptr, h, nullptr);
    transpose_f2f<<<dim3(24, 18, 8), tb, 0, stream>>>(h, (float*)d_out, 576, 768, 442368, 442368);
}